// Round 1
// baseline (21739.043 us; speedup 1.0000x reference)
//
#include <hip/hip_runtime.h>
#include <math.h>

#define NBATCH 32
#define SEQ 197
#define DIM 768
#define NHEAD 12
#define DH 64
#define MDIM 3072
#define NLAYER 12
#define NPATCH 196
#define NOUT 1000

// ---------------- reduction helpers ----------------
__device__ __forceinline__ float block_sum256(float v, float* tmp) {
#pragma unroll
    for (int o = 32; o > 0; o >>= 1) v += __shfl_down(v, o, 64);
    int wave = threadIdx.x >> 6, lane = threadIdx.x & 63;
    __syncthreads();
    if (lane == 0) tmp[wave] = v;
    __syncthreads();
    return tmp[0] + tmp[1] + tmp[2] + tmp[3];
}

__device__ __forceinline__ float block_max256(float v, float* tmp) {
#pragma unroll
    for (int o = 32; o > 0; o >>= 1) v = fmaxf(v, __shfl_down(v, o, 64));
    int wave = threadIdx.x >> 6, lane = threadIdx.x & 63;
    __syncthreads();
    if (lane == 0) tmp[wave] = v;
    __syncthreads();
    return fmaxf(fmaxf(tmp[0], tmp[1]), fmaxf(tmp[2], tmp[3]));
}

// ---------------- cls + pos init ----------------
__global__ __launch_bounds__(256) void cls_pos_kernel(const float* __restrict__ cls,
                                                      const float* __restrict__ pos,
                                                      float* __restrict__ x) {
    int b = blockIdx.x, tid = threadIdx.x;
#pragma unroll
    for (int i = 0; i < 3; i++) {
        int c = tid + i * 256;
        x[(size_t)b * SEQ * DIM + c] = cls[c] + pos[c];
    }
}

// ---------------- patch-embed GEMM (gathered A) ----------------
// out rows: x[b*197 + 1 + p], val = patch . Wp[n] + bp[n] + pos[1+p][n]
__global__ __launch_bounds__(256) void gemm_patch(const float* __restrict__ images,
                                                  const float* __restrict__ Wp,
                                                  const float* __restrict__ bp,
                                                  const float* __restrict__ pos,
                                                  float* __restrict__ x) {
    __shared__ float As[8][128];
    __shared__ float Bs[8][128];
    int tid = threadIdx.x;
    int bm = blockIdx.x * 128, bn = blockIdx.y * 128;
    int lrow = tid >> 1;
    int lk = (tid & 1) * 4;
    int tx = tid & 15, ty = tid >> 4;
    float acc[8][8] = {};

    int gm = bm + lrow;                 // 0..6271 always valid (M = 6272)
    int b = gm / NPATCH, p = gm % NPATCH;
    int py = p / 14, px = p % 14;
    const float* imgbase = images + (size_t)b * 3 * 224 * 224 + (size_t)py * 16 * 224 + px * 16;

    for (int k0 = 0; k0 < 768; k0 += 8) {
        int k = k0 + lk;
        int c = k >> 8, ii = (k >> 4) & 15, j = k & 15;
        float4 a4 = *(const float4*)(imgbase + ((size_t)c * 224 + ii) * 224 + j);
        float4 b4 = *(const float4*)(Wp + (size_t)(bn + lrow) * 768 + k);
        __syncthreads();
        As[lk + 0][lrow] = a4.x; As[lk + 1][lrow] = a4.y; As[lk + 2][lrow] = a4.z; As[lk + 3][lrow] = a4.w;
        Bs[lk + 0][lrow] = b4.x; Bs[lk + 1][lrow] = b4.y; Bs[lk + 2][lrow] = b4.z; Bs[lk + 3][lrow] = b4.w;
        __syncthreads();
#pragma unroll
        for (int kk = 0; kk < 8; kk++) {
            float a[8], bb[8];
            *(float4*)(a)     = *(const float4*)(&As[kk][ty * 8]);
            *(float4*)(a + 4) = *(const float4*)(&As[kk][ty * 8 + 4]);
            *(float4*)(bb)     = *(const float4*)(&Bs[kk][tx * 8]);
            *(float4*)(bb + 4) = *(const float4*)(&Bs[kk][tx * 8 + 4]);
#pragma unroll
            for (int i = 0; i < 8; i++)
#pragma unroll
                for (int j2 = 0; j2 < 8; j2++) acc[i][j2] = fmaf(a[i], bb[j2], acc[i][j2]);
        }
    }
#pragma unroll
    for (int i = 0; i < 8; i++) {
        int gm2 = bm + ty * 8 + i;
        int b2 = gm2 / NPATCH, p2 = gm2 % NPATCH;
        size_t orow = (size_t)(b2 * SEQ + 1 + p2) * DIM;
#pragma unroll
        for (int j = 0; j < 8; j++) {
            int gn = bn + tx * 8 + j;
            x[orow + gn] = acc[i][j] + bp[gn] + pos[(size_t)(1 + p2) * DIM + gn];
        }
    }
}

// ---------------- LayerNorm (optional residual add, optional x write-back) ----------------
__global__ __launch_bounds__(256) void ln_kernel(const float* __restrict__ x_in,
                                                 const float* __restrict__ addv,
                                                 float* __restrict__ x_out,
                                                 float* __restrict__ h_out,
                                                 const float* __restrict__ g,
                                                 const float* __restrict__ bb) {
    __shared__ float tmp[4];
    size_t row = blockIdx.x;
    int tid = threadIdx.x;
    const float* xr = x_in + row * DIM;
    float vals[3];
    float s = 0;
#pragma unroll
    for (int i = 0; i < 3; i++) {
        int c = tid + i * 256;
        float v = xr[c];
        if (addv) v += addv[row * DIM + c];
        vals[i] = v;
        s += v;
    }
    float mean = block_sum256(s, tmp) * (1.0f / 768.0f);
    float vs = 0;
#pragma unroll
    for (int i = 0; i < 3; i++) { float d = vals[i] - mean; vs += d * d; }
    float var = block_sum256(vs, tmp) * (1.0f / 768.0f);
    float inv = rsqrtf(var + 1e-5f);
#pragma unroll
    for (int i = 0; i < 3; i++) {
        int c = tid + i * 256;
        h_out[row * DIM + c] = (vals[i] - mean) * inv * g[c] + bb[c];
        if (x_out) x_out[row * DIM + c] = vals[i];
    }
}

// ---------------- QKV projection (per-head 64x64) ----------------
__global__ __launch_bounds__(256) void qkv_kernel(const float* __restrict__ h,
                                                  const float* __restrict__ Wq, const float* __restrict__ bq,
                                                  const float* __restrict__ Wk, const float* __restrict__ bk,
                                                  const float* __restrict__ Wv, const float* __restrict__ bv,
                                                  float* __restrict__ q, float* __restrict__ k, float* __restrict__ v) {
    __shared__ float ws[3][64][65];
    __shared__ float hs[8][64];
    int b = blockIdx.x, s0 = blockIdx.y * 8, head = blockIdx.z;
    int tid = threadIdx.x;
    const float* Wt[3] = {Wq + (size_t)head * 4096, Wk + (size_t)head * 4096, Wv + (size_t)head * 4096};
#pragma unroll
    for (int t = 0; t < 3; t++) {
        const float* W = Wt[t];
#pragma unroll
        for (int p = 0; p < 4; p++) {
            int f = tid + p * 256;                  // 0..1023 float4s
            float4 w4 = *(const float4*)(W + (size_t)f * 4);
            int e = (f * 4) >> 6, d = (f * 4) & 63;
            ws[t][e][d] = w4.x; ws[t][e][d + 1] = w4.y; ws[t][e][d + 2] = w4.z; ws[t][e][d + 3] = w4.w;
        }
    }
#pragma unroll
    for (int p = 0; p < 2; p++) {
        int f = tid + p * 256;
        int sl = f >> 6, d = f & 63;
        int s = s0 + sl;
        hs[sl][d] = (s < SEQ) ? h[((size_t)(b * SEQ + s)) * DIM + head * DH + d] : 0.f;
    }
    __syncthreads();
#pragma unroll
    for (int p = 0; p < 2; p++) {
        int idx = tid + p * 256;
        int sl = idx >> 6, e = idx & 63;
        int s = s0 + sl;
        if (s >= SEQ) continue;
        float aq = bq[head * DH + e], ak = bk[head * DH + e], av = bv[head * DH + e];
#pragma unroll 8
        for (int d = 0; d < 64; d++) {
            float hv = hs[sl][d];
            aq = fmaf(hv, ws[0][e][d], aq);
            ak = fmaf(hv, ws[1][e][d], ak);
            av = fmaf(hv, ws[2][e][d], av);
        }
        size_t oidx = ((size_t)(b * SEQ + s)) * DIM + head * DH + e;
        q[oidx] = aq; k[oidx] = ak; v[oidx] = av;
    }
}

// ---------------- fused attention: one block per (b, head) ----------------
__global__ __launch_bounds__(256) void attn_kernel(const float* __restrict__ q,
                                                   const float* __restrict__ kg,
                                                   const float* __restrict__ vg,
                                                   float* __restrict__ o) {
    __shared__ float Ks[SEQ][65];
    __shared__ float Vs[SEQ][65];
    __shared__ float qs[4][64];
    __shared__ float ps[4][200];
    int b = blockIdx.x, head = blockIdx.y;
    int tid = threadIdx.x;
    size_t base = (size_t)(b * SEQ) * DIM + head * DH;
#pragma unroll
    for (int p = 0; p < 50; p++) {
        int f = tid + p * 256;
        if (f < SEQ * 64) {
            int r = f >> 6, d = f & 63;
            Ks[r][d] = kg[base + (size_t)r * DIM + d];
            Vs[r][d] = vg[base + (size_t)r * DIM + d];
        }
    }
    __syncthreads();
    int wave = tid >> 6, lane = tid & 63;
    for (int qi = wave; qi < SEQ; qi += 4) {
        qs[wave][lane] = q[base + (size_t)qi * DIM + lane];
        float sc[4];
        float mx = -1e30f;
#pragma unroll
        for (int c = 0; c < 4; c++) {
            int j = lane + c * 64;
            float s = 0;
            if (j < SEQ) {
#pragma unroll 8
                for (int d = 0; d < 64; d++) s = fmaf(qs[wave][d], Ks[j][d], s);
                s *= 0.125f;
                mx = fmaxf(mx, s);
            }
            sc[c] = s;
        }
#pragma unroll
        for (int off = 32; off > 0; off >>= 1) mx = fmaxf(mx, __shfl_xor(mx, off, 64));
        float sum = 0;
#pragma unroll
        for (int c = 0; c < 4; c++) {
            int j = lane + c * 64;
            if (j < SEQ) {
                float pv = expf(sc[c] - mx);
                ps[wave][j] = pv;
                sum += pv;
            }
        }
#pragma unroll
        for (int off = 32; off > 0; off >>= 1) sum += __shfl_xor(sum, off, 64);
        float invs = 1.0f / sum;
        float acc = 0;
        for (int j = 0; j < SEQ; j++) acc = fmaf(ps[wave][j], Vs[j][lane], acc);
        o[base + (size_t)qi * DIM + lane] = acc * invs;
    }
}

// ---------------- generic NT GEMM: C = epi(A @ Bw^T + bias)  ----------------
// MODE 1: gelu(v) -> C ; MODE 2: v + res -> C
template <int MODE>
__global__ __launch_bounds__(256) void gemm_nt(const float* __restrict__ A,
                                               const float* __restrict__ Bw,
                                               const float* __restrict__ bias,
                                               float* __restrict__ C,
                                               const float* __restrict__ res,
                                               int M, int N, int K) {
    __shared__ float As[8][128];
    __shared__ float Bs[8][128];
    int tid = threadIdx.x;
    int bm = blockIdx.x * 128, bn = blockIdx.y * 128;
    int lrow = tid >> 1;
    int lk = (tid & 1) * 4;
    int tx = tid & 15, ty = tid >> 4;
    float acc[8][8] = {};

    for (int k0 = 0; k0 < K; k0 += 8) {
        float4 a4 = make_float4(0.f, 0.f, 0.f, 0.f);
        int gm = bm + lrow;
        if (gm < M) a4 = *(const float4*)(A + (size_t)gm * K + k0 + lk);
        float4 b4 = *(const float4*)(Bw + (size_t)(bn + lrow) * K + k0 + lk);
        __syncthreads();
        As[lk + 0][lrow] = a4.x; As[lk + 1][lrow] = a4.y; As[lk + 2][lrow] = a4.z; As[lk + 3][lrow] = a4.w;
        Bs[lk + 0][lrow] = b4.x; Bs[lk + 1][lrow] = b4.y; Bs[lk + 2][lrow] = b4.z; Bs[lk + 3][lrow] = b4.w;
        __syncthreads();
#pragma unroll
        for (int kk = 0; kk < 8; kk++) {
            float a[8], bb[8];
            *(float4*)(a)     = *(const float4*)(&As[kk][ty * 8]);
            *(float4*)(a + 4) = *(const float4*)(&As[kk][ty * 8 + 4]);
            *(float4*)(bb)     = *(const float4*)(&Bs[kk][tx * 8]);
            *(float4*)(bb + 4) = *(const float4*)(&Bs[kk][tx * 8 + 4]);
#pragma unroll
            for (int i = 0; i < 8; i++)
#pragma unroll
                for (int j = 0; j < 8; j++) acc[i][j] = fmaf(a[i], bb[j], acc[i][j]);
        }
    }
#pragma unroll
    for (int i = 0; i < 8; i++) {
        int gm = bm + ty * 8 + i;
        if (gm < M) {
#pragma unroll
            for (int j = 0; j < 8; j++) {
                int gn = bn + tx * 8 + j;
                float vb = acc[i][j] + bias[gn];
                if (MODE == 1) {
                    C[(size_t)gm * N + gn] = 0.5f * vb * (1.0f + erff(vb * 0.70710678118f));
                } else {
                    C[(size_t)gm * N + gn] = vb + res[(size_t)gm * N + gn];
                }
            }
        }
    }
}

// ---------------- classifier head ----------------
__global__ __launch_bounds__(256) void head_kernel(const float* __restrict__ x,
                                                   const float* __restrict__ Wh,
                                                   const float* __restrict__ bh,
                                                   float* __restrict__ logits) {
    __shared__ float xs[768];
    int b = blockIdx.x;
    int tid = threadIdx.x;
#pragma unroll
    for (int i = 0; i < 3; i++) xs[tid + i * 256] = x[(size_t)b * SEQ * DIM + tid + i * 256];
    __syncthreads();
    int wave = tid >> 6, lane = tid & 63;
    int o = blockIdx.y * 4 + wave;
    if (o < NOUT) {
        float acc = 0;
#pragma unroll
        for (int t = 0; t < 12; t++) {
            int d = lane + t * 64;
            acc = fmaf(xs[d], Wh[(size_t)o * DIM + d], acc);
        }
#pragma unroll
        for (int off = 32; off > 0; off >>= 1) acc += __shfl_down(acc, off, 64);
        if (lane == 0) logits[b * NOUT + o] = acc + bh[o];
    }
}

__global__ __launch_bounds__(256) void softmax_kernel(const float* __restrict__ logits,
                                                      float* __restrict__ out) {
    __shared__ float tmp[4];
    int b = blockIdx.x, tid = threadIdx.x;
    float vals[4];
    float mx = -1e30f;
#pragma unroll
    for (int i = 0; i < 4; i++) {
        int c = tid + i * 256;
        vals[i] = (c < NOUT) ? logits[b * NOUT + c] : -1e30f;
        mx = fmaxf(mx, vals[i]);
    }
    mx = block_max256(mx, tmp);
    float s = 0;
#pragma unroll
    for (int i = 0; i < 4; i++) {
        int c = tid + i * 256;
        if (c < NOUT) {
            vals[i] = expf(vals[i] - mx);
            s += vals[i];
        } else vals[i] = 0.f;
    }
    s = block_sum256(s, tmp);
    float invs = 1.0f / s;
#pragma unroll
    for (int i = 0; i < 4; i++) {
        int c = tid + i * 256;
        if (c < NOUT) out[b * NOUT + c] = vals[i] * invs;
    }
}

extern "C" void kernel_launch(void* const* d_in, const int* in_sizes, int n_in,
                              void* d_out, int out_size, void* d_ws, size_t ws_size,
                              hipStream_t stream) {
    const float* images = (const float*)d_in[0];
    const float* Wp   = (const float*)d_in[1];
    const float* bp   = (const float*)d_in[2];
    const float* cls  = (const float*)d_in[3];
    const float* pos  = (const float*)d_in[4];
    const float* ln1g = (const float*)d_in[5];
    const float* ln1b = (const float*)d_in[6];
    const float* Wq   = (const float*)d_in[7];
    const float* bq   = (const float*)d_in[8];
    const float* Wk   = (const float*)d_in[9];
    const float* bk   = (const float*)d_in[10];
    const float* Wv   = (const float*)d_in[11];
    const float* bv   = (const float*)d_in[12];
    const float* ln2g = (const float*)d_in[13];
    const float* ln2b = (const float*)d_in[14];
    const float* W1   = (const float*)d_in[15];
    const float* b1   = (const float*)d_in[16];
    const float* W2   = (const float*)d_in[17];
    const float* b2   = (const float*)d_in[18];
    const float* Wh   = (const float*)d_in[19];
    const float* bh   = (const float*)d_in[20];
    float* out = (float*)d_out;

    const size_t NX = (size_t)NBATCH * SEQ * DIM;   // 4,841,472
    float* ws = (float*)d_ws;
    float* x   = ws;
    float* h   = x + NX;
    float* qb  = h + NX;
    float* kb  = qb + NX;
    float* vb  = kb + NX;
    float* mid = vb + NX;
    float* logits = mid + (size_t)NBATCH * SEQ * MDIM;

    cls_pos_kernel<<<dim3(32), dim3(256), 0, stream>>>(cls, pos, x);
    gemm_patch<<<dim3(49, 6), dim3(256), 0, stream>>>(images, Wp, bp, pos, x);

    for (int l = 0; l < NLAYER; l++) {
        ln_kernel<<<dim3(NBATCH * SEQ), dim3(256), 0, stream>>>(
            x, nullptr, nullptr, h, ln1g + l * DIM, ln1b + l * DIM);
        qkv_kernel<<<dim3(32, 25, 12), dim3(256), 0, stream>>>(
            h, Wq + (size_t)l * NHEAD * DH * DH, bq + l * NHEAD * DH,
            Wk + (size_t)l * NHEAD * DH * DH, bk + l * NHEAD * DH,
            Wv + (size_t)l * NHEAD * DH * DH, bv + l * NHEAD * DH,
            qb, kb, vb);
        attn_kernel<<<dim3(32, 12), dim3(256), 0, stream>>>(qb, kb, vb, h);
        ln_kernel<<<dim3(NBATCH * SEQ), dim3(256), 0, stream>>>(
            x, h, x, qb, ln2g + l * DIM, ln2b + l * DIM);
        gemm_nt<1><<<dim3(50, 24), dim3(256), 0, stream>>>(
            qb, W1 + (size_t)l * MDIM * DIM, b1 + l * MDIM, mid, nullptr,
            NBATCH * SEQ, MDIM, DIM);
        gemm_nt<2><<<dim3(50, 6), dim3(256), 0, stream>>>(
            mid, W2 + (size_t)l * DIM * MDIM, b2 + l * DIM, x, x,
            NBATCH * SEQ, DIM, MDIM);
    }

    head_kernel<<<dim3(32, 250), dim3(256), 0, stream>>>(x, Wh, bh, logits);
    softmax_kernel<<<dim3(32), dim3(256), 0, stream>>>(logits, out);
}

// Round 2
// 3087.672 us; speedup vs baseline: 7.0406x; 7.0406x over previous
//
#include <hip/hip_runtime.h>
#include <math.h>
#include <stdint.h>

#define NBATCH 32
#define SEQ 197
#define DIM 768
#define NHEAD 12
#define DH 64
#define MDIM 3072
#define NLAYER 12
#define NPATCH 196
#define NOUT 1000
#define MROWS (NBATCH * SEQ)   // 6304

typedef __bf16 bf16x8 __attribute__((ext_vector_type(8)));
typedef float f32x4 __attribute__((ext_vector_type(4)));

__device__ __forceinline__ unsigned short f2bf(float f) {
    unsigned u = __float_as_uint(f);
    unsigned r = u + 0x7fffu + ((u >> 16) & 1u);
    return (unsigned short)(r >> 16);
}

__device__ __forceinline__ f32x4 mfma16(bf16x8 a, bf16x8 b, f32x4 c) {
    return __builtin_amdgcn_mfma_f32_16x16x32_bf16(a, b, c, 0, 0, 0);
}

// async global->LDS 16B: lds pointer must be wave-uniform; HW writes lane l at base + l*16
__device__ __forceinline__ void gload_lds16(const void* g, const void* lds) {
    __builtin_amdgcn_global_load_lds(
        (const __attribute__((address_space(1))) void*)(uintptr_t)g,
        (__attribute__((address_space(3))) void*)(uint32_t)(uintptr_t)lds,
        16, 0, 0);
}

// ---------------- fp32 -> bf16 converters ----------------
__global__ __launch_bounds__(256) void cvt4(const float* __restrict__ src,
                                            unsigned short* __restrict__ dst, int n4) {
    int stride = gridDim.x * 256;
    for (int i = blockIdx.x * 256 + threadIdx.x; i < n4; i += stride) {
        float4 f = *(const float4*)(src + (size_t)i * 4);
        ushort4 o;
        o.x = f2bf(f.x); o.y = f2bf(f.y); o.z = f2bf(f.z); o.w = f2bf(f.w);
        *(ushort4*)(dst + (size_t)i * 4) = o;
    }
}

// gather Wq/Wk/Wv [L][H][e][d] -> wqkvb [L][H][3*64 rows][64] bf16
__global__ __launch_bounds__(256) void cvt_qkvw(const float* __restrict__ Wq,
                                                const float* __restrict__ Wk,
                                                const float* __restrict__ Wv,
                                                unsigned short* __restrict__ dst) {
    const int n = NLAYER * NHEAD * 3 * 64 * 64;
    int stride = gridDim.x * 256;
    for (int i = blockIdx.x * 256 + threadIdx.x; i < n; i += stride) {
        int d = i & 63, e = (i >> 6) & 63;
        int v = i >> 12;
        int t = v % 3, hh = (v / 3) % NHEAD, l = v / (3 * NHEAD);
        const float* src = (t == 0) ? Wq : (t == 1) ? Wk : Wv;
        dst[i] = f2bf(src[(((size_t)(l * NHEAD + hh)) * 64 + e) * 64 + d]);
    }
}

// ---------------- cls + pos init ----------------
__global__ __launch_bounds__(256) void cls_pos_kernel(const float* __restrict__ cls,
                                                      const float* __restrict__ pos,
                                                      float* __restrict__ x) {
    int b = blockIdx.x, tid = threadIdx.x;
#pragma unroll
    for (int i = 0; i < 3; i++) {
        int c = tid + i * 256;
        x[(size_t)b * SEQ * DIM + c] = cls[c] + pos[c];
    }
}

// ---------------- patch-embed GEMM (fp32, unchanged) ----------------
__global__ __launch_bounds__(256) void gemm_patch(const float* __restrict__ images,
                                                  const float* __restrict__ Wp,
                                                  const float* __restrict__ bp,
                                                  const float* __restrict__ pos,
                                                  float* __restrict__ x) {
    __shared__ float As[8][128];
    __shared__ float Bs[8][128];
    int tid = threadIdx.x;
    int bm = blockIdx.x * 128, bn = blockIdx.y * 128;
    int lrow = tid >> 1;
    int lk = (tid & 1) * 4;
    int tx = tid & 15, ty = tid >> 4;
    float acc[8][8] = {};

    int gm = bm + lrow;
    int b = gm / NPATCH, p = gm % NPATCH;
    int py = p / 14, px = p % 14;
    const float* imgbase = images + (size_t)b * 3 * 224 * 224 + (size_t)py * 16 * 224 + px * 16;

    for (int k0 = 0; k0 < 768; k0 += 8) {
        int k = k0 + lk;
        int c = k >> 8, ii = (k >> 4) & 15, j = k & 15;
        float4 a4 = *(const float4*)(imgbase + ((size_t)c * 224 + ii) * 224 + j);
        float4 b4 = *(const float4*)(Wp + (size_t)(bn + lrow) * 768 + k);
        __syncthreads();
        As[lk + 0][lrow] = a4.x; As[lk + 1][lrow] = a4.y; As[lk + 2][lrow] = a4.z; As[lk + 3][lrow] = a4.w;
        Bs[lk + 0][lrow] = b4.x; Bs[lk + 1][lrow] = b4.y; Bs[lk + 2][lrow] = b4.z; Bs[lk + 3][lrow] = b4.w;
        __syncthreads();
#pragma unroll
        for (int kk = 0; kk < 8; kk++) {
            float a[8], bb[8];
            *(float4*)(a)     = *(const float4*)(&As[kk][ty * 8]);
            *(float4*)(a + 4) = *(const float4*)(&As[kk][ty * 8 + 4]);
            *(float4*)(bb)     = *(const float4*)(&Bs[kk][tx * 8]);
            *(float4*)(bb + 4) = *(const float4*)(&Bs[kk][tx * 8 + 4]);
#pragma unroll
            for (int i = 0; i < 8; i++)
#pragma unroll
                for (int j2 = 0; j2 < 8; j2++) acc[i][j2] = fmaf(a[i], bb[j2], acc[i][j2]);
        }
    }
#pragma unroll
    for (int i = 0; i < 8; i++) {
        int gm2 = bm + ty * 8 + i;
        int b2 = gm2 / NPATCH, p2 = gm2 % NPATCH;
        size_t orow = (size_t)(b2 * SEQ + 1 + p2) * DIM;
#pragma unroll
        for (int j = 0; j < 8; j++) {
            int gn = bn + tx * 8 + j;
            x[orow + gn] = acc[i][j] + bp[gn] + pos[(size_t)(1 + p2) * DIM + gn];
        }
    }
}

// ---------------- wave-per-row LayerNorm, bf16 h out, optional residual ----------------
template <int RES>
__global__ __launch_bounds__(256) void ln_wave(const float* __restrict__ x_in,
                                               const float* __restrict__ addv,
                                               float* __restrict__ x_out,
                                               unsigned short* __restrict__ h_out,
                                               const float* __restrict__ g,
                                               const float* __restrict__ bb) {
    int w = threadIdx.x >> 6, l = threadIdx.x & 63;
    size_t row = (size_t)blockIdx.x * 4 + w;
    const float* xr = x_in + row * DIM;
    float4 v[3];
    float s = 0.f;
#pragma unroll
    for (int u = 0; u < 3; u++) {
        int c = u * 256 + l * 4;
        v[u] = *(const float4*)(xr + c);
        if (RES) {
            float4 a4 = *(const float4*)(addv + row * DIM + c);
            v[u].x += a4.x; v[u].y += a4.y; v[u].z += a4.z; v[u].w += a4.w;
        }
        s += v[u].x + v[u].y + v[u].z + v[u].w;
    }
#pragma unroll
    for (int o = 1; o < 64; o <<= 1) s += __shfl_xor(s, o, 64);
    float mean = s * (1.0f / 768.0f);
    float s2 = 0.f;
#pragma unroll
    for (int u = 0; u < 3; u++) {
        float dx = v[u].x - mean, dy = v[u].y - mean, dz = v[u].z - mean, dw = v[u].w - mean;
        s2 += dx * dx + dy * dy + dz * dz + dw * dw;
    }
#pragma unroll
    for (int o = 1; o < 64; o <<= 1) s2 += __shfl_xor(s2, o, 64);
    float inv = rsqrtf(s2 * (1.0f / 768.0f) + 1e-5f);
#pragma unroll
    for (int u = 0; u < 3; u++) {
        int c = u * 256 + l * 4;
        float4 g4 = *(const float4*)(g + c);
        float4 b4 = *(const float4*)(bb + c);
        ushort4 o;
        o.x = f2bf((v[u].x - mean) * inv * g4.x + b4.x);
        o.y = f2bf((v[u].y - mean) * inv * g4.y + b4.y);
        o.z = f2bf((v[u].z - mean) * inv * g4.z + b4.z);
        o.w = f2bf((v[u].w - mean) * inv * g4.w + b4.w);
        *(ushort4*)(h_out + row * DIM + c) = o;
        if (RES) *(float4*)(x_out + row * DIM + c) = v[u];
    }
}

// ---------------- QKV projection: per-head MFMA, K=64 ----------------
__global__ __launch_bounds__(256) void qkv_mfma(const unsigned short* __restrict__ hbf,
                                                const unsigned short* __restrict__ wqkv,
                                                const float* __restrict__ bq,
                                                const float* __restrict__ bk,
                                                const float* __restrict__ bv,
                                                unsigned short* __restrict__ q,
                                                unsigned short* __restrict__ k,
                                                unsigned short* __restrict__ v) {
    __shared__ __align__(16) unsigned short As[2 * 128 * 32];
    __shared__ __align__(16) unsigned short Bs[2 * 192 * 32];
    const int bm = blockIdx.x * 128, hd = blockIdx.y;
    const int t = threadIdx.x, l = t & 63, w = t >> 6;
    const unsigned short* wh = wqkv + (size_t)hd * 12288;

#pragma unroll
    for (int i = 0; i < 4; i++) {
        int p = t + i * 256;
        int kt = p >> 9, r = (p >> 2) & 127, kc = p & 3;
        int grow = min(bm + r, MROWS - 1);
        gload_lds16(hbf + (size_t)grow * DIM + hd * 64 + kt * 32 + kc * 8,
                    As + (size_t)(i * 256 + w * 64) * 8);
    }
#pragma unroll
    for (int i = 0; i < 6; i++) {
        int p = t + i * 256;
        int kt = p / 768, rem = p - kt * 768;
        int r = rem >> 2, kc = rem & 3;
        gload_lds16(wh + (size_t)r * 64 + kt * 32 + kc * 8,
                    Bs + (size_t)(i * 256 + w * 64) * 8);
    }
    __syncthreads();

    f32x4 acc[4][6] = {};
    const int wr = w >> 1, wc = w & 1;
    const int lr = l & 15, lk = (l >> 4) * 8;
#pragma unroll
    for (int ks = 0; ks < 2; ks++) {
        bf16x8 a[4], bfr[6];
#pragma unroll
        for (int m = 0; m < 4; m++)
            a[m] = *(const bf16x8*)(As + ks * 4096 + (wr * 64 + m * 16 + lr) * 32 + lk);
#pragma unroll
        for (int n = 0; n < 6; n++)
            bfr[n] = *(const bf16x8*)(Bs + ks * 6144 + (wc * 96 + n * 16 + lr) * 32 + lk);
#pragma unroll
        for (int m = 0; m < 4; m++)
#pragma unroll
            for (int n = 0; n < 6; n++)
                acc[m][n] = mfma16(a[m], bfr[n], acc[m][n]);
    }
#pragma unroll
    for (int n = 0; n < 6; n++) {
        int c = wc * 96 + n * 16 + lr;
        int tt = c >> 6, e = c & 63;
        const float* bias = (tt == 0) ? bq : (tt == 1) ? bk : bv;
        unsigned short* outp = (tt == 0) ? q : (tt == 1) ? k : v;
        float bval = bias[hd * 64 + e];
#pragma unroll
        for (int m = 0; m < 4; m++) {
#pragma unroll
            for (int r = 0; r < 4; r++) {
                int gm = bm + wr * 64 + m * 16 + (l >> 4) * 4 + r;
                if (gm < MROWS) outp[(size_t)gm * DIM + hd * 64 + e] = f2bf(acc[m][n][r] + bval);
            }
        }
    }
}

// ---------------- fused attention: MFMA, swapped QK^T, per-wave P in LDS ----------------
__global__ __launch_bounds__(256) void attn_mfma(const unsigned short* __restrict__ qg,
                                                 const unsigned short* __restrict__ kg,
                                                 const unsigned short* __restrict__ vg,
                                                 float* __restrict__ o) {
    __shared__ __align__(16) unsigned short Vt[64][232];   // V transposed [d][j], pad to 232
    __shared__ __align__(16) unsigned short P[4][16][232]; // per-wave P [q][j]
    const int b = blockIdx.x, hd = blockIdx.y;
    const int t = threadIdx.x, l = t & 63, w = t >> 6;
    const size_t base = ((size_t)b * SEQ) * DIM + hd * DH;

    for (int idx = t; idx < 224 * 16; idx += 256) {
        int j = idx >> 4, dg = idx & 15;
        if (j < SEQ) {
            ushort4 v4 = *(const ushort4*)(vg + base + (size_t)j * DIM + dg * 4);
            Vt[dg * 4 + 0][j] = v4.x; Vt[dg * 4 + 1][j] = v4.y;
            Vt[dg * 4 + 2][j] = v4.z; Vt[dg * 4 + 3][j] = v4.w;
        } else {
            Vt[dg * 4 + 0][j] = 0; Vt[dg * 4 + 1][j] = 0;
            Vt[dg * 4 + 2][j] = 0; Vt[dg * 4 + 3][j] = 0;
        }
    }
    {   // zero this wave's P padding cols 208..223
        int qq = l & 15, jj = 208 + (l >> 4) * 4;
        P[w][qq][jj] = 0; P[w][qq][jj + 1] = 0; P[w][qq][jj + 2] = 0; P[w][qq][jj + 3] = 0;
    }
    __syncthreads();

    const int lr = l & 15, lk4 = (l >> 4);
    for (int qt = w; qt < 13; qt += 4) {
        int qrow = min(qt * 16 + lr, SEQ - 1);
        const unsigned short* qp = qg + base + (size_t)qrow * DIM + lk4 * 8;
        bf16x8 q0 = *(const bf16x8*)qp;
        bf16x8 q1 = *(const bf16x8*)(qp + 32);
        f32x4 st[13];
#pragma unroll
        for (int jt = 0; jt < 13; jt++) st[jt] = (f32x4){0.f, 0.f, 0.f, 0.f};
#pragma unroll
        for (int jt = 0; jt < 13; jt++) {
            int jrow = min(jt * 16 + lr, SEQ - 1);
            const unsigned short* kp = kg + base + (size_t)jrow * DIM + lk4 * 8;
            bf16x8 k0 = *(const bf16x8*)kp;
            bf16x8 k1 = *(const bf16x8*)(kp + 32);
            st[jt] = mfma16(k0, q0, st[jt]);   // S^T[j][q]
            st[jt] = mfma16(k1, q1, st[jt]);
        }
        float mx = -1e30f;
#pragma unroll
        for (int jt = 0; jt < 13; jt++)
#pragma unroll
            for (int r = 0; r < 4; r++) {
                int j = jt * 16 + lk4 * 4 + r;
                float sv = st[jt][r] * 0.125f;
                st[jt][r] = (j < SEQ) ? sv : -1e30f;
                mx = fmaxf(mx, st[jt][r]);
            }
        mx = fmaxf(mx, __shfl_xor(mx, 16, 64));
        mx = fmaxf(mx, __shfl_xor(mx, 32, 64));
        float sum = 0.f;
#pragma unroll
        for (int jt = 0; jt < 13; jt++)
#pragma unroll
            for (int r = 0; r < 4; r++) {
                float p = __expf(st[jt][r] - mx);
                st[jt][r] = p;
                sum += p;
            }
        sum += __shfl_xor(sum, 16, 64);
        sum += __shfl_xor(sum, 32, 64);
        float inv = 1.0f / sum;
#pragma unroll
        for (int jt = 0; jt < 13; jt++) {
            ushort4 pk;
            pk.x = f2bf(st[jt][0] * inv); pk.y = f2bf(st[jt][1] * inv);
            pk.z = f2bf(st[jt][2] * inv); pk.w = f2bf(st[jt][3] * inv);
            *(ushort4*)&P[w][lr][jt * 16 + lk4 * 4] = pk;
        }
        f32x4 acc[4] = {};
#pragma unroll
        for (int kt = 0; kt < 7; kt++) {
            bf16x8 pa = *(const bf16x8*)&P[w][lr][kt * 32 + lk4 * 8];
#pragma unroll
            for (int nt = 0; nt < 4; nt++) {
                bf16x8 bv = *(const bf16x8*)&Vt[nt * 16 + lr][kt * 32 + lk4 * 8];
                acc[nt] = mfma16(pa, bv, acc[nt]);
            }
        }
#pragma unroll
        for (int nt = 0; nt < 4; nt++)
#pragma unroll
            for (int r = 0; r < 4; r++) {
                int qq = qt * 16 + lk4 * 4 + r;
                if (qq < SEQ) o[base + (size_t)qq * DIM + nt * 16 + lr] = acc[nt][r];
            }
    }
}

// ---------------- bf16 MFMA NT GEMM, 128x128 tile, BK=32 (m97 structure) ----------------
// MODE 1: gelu(acc+bias) -> bf16 C ; MODE 2: acc+bias+res -> fp32 C
template <int MODE>
__global__ __launch_bounds__(256) void gemm_bf(const unsigned short* __restrict__ A,
                                               const unsigned short* __restrict__ Bw,
                                               const float* __restrict__ bias,
                                               void* __restrict__ Cout,
                                               const float* __restrict__ res,
                                               int M, int N, int K) {
    __shared__ __align__(16) unsigned short As[128 * 32];
    __shared__ __align__(16) unsigned short Bs[128 * 32];
    const int t = threadIdx.x, l = t & 63, w = t >> 6;
    const int bm = blockIdx.x * 128, bn = blockIdx.y * 128;
    const int wr = w >> 1, wc = w & 1;
    f32x4 acc[4][4] = {};

    const int ra0 = t >> 2, ka0 = (t & 3) * 8;
    const int ra1 = (t + 256) >> 2, ka1 = ((t + 256) & 3) * 8;
    const unsigned short* Ar0 = A + (size_t)min(bm + ra0, M - 1) * K + ka0;
    const unsigned short* Ar1 = A + (size_t)min(bm + ra1, M - 1) * K + ka1;
    const unsigned short* Br0 = Bw + (size_t)(bn + ra0) * K + ka0;
    const unsigned short* Br1 = Bw + (size_t)(bn + ra1) * K + ka1;
    unsigned short* lA0 = As + (size_t)(0 * 256 + w * 64) * 8;
    unsigned short* lA1 = As + (size_t)(1 * 256 + w * 64) * 8;
    unsigned short* lB0 = Bs + (size_t)(0 * 256 + w * 64) * 8;
    unsigned short* lB1 = Bs + (size_t)(1 * 256 + w * 64) * 8;
    const int lr = l & 15, lk = (l >> 4) * 8;

    for (int k0 = 0; k0 < K; k0 += 32) {
        __syncthreads();
        gload_lds16(Ar0 + k0, lA0);
        gload_lds16(Ar1 + k0, lA1);
        gload_lds16(Br0 + k0, lB0);
        gload_lds16(Br1 + k0, lB1);
        __syncthreads();
        bf16x8 a[4], bfr[4];
#pragma unroll
        for (int m = 0; m < 4; m++)
            a[m] = *(const bf16x8*)(As + (wr * 64 + m * 16 + lr) * 32 + lk);
#pragma unroll
        for (int n = 0; n < 4; n++)
            bfr[n] = *(const bf16x8*)(Bs + (wc * 64 + n * 16 + lr) * 32 + lk);
#pragma unroll
        for (int m = 0; m < 4; m++)
#pragma unroll
            for (int n = 0; n < 4; n++)
                acc[m][n] = mfma16(a[m], bfr[n], acc[m][n]);
    }

#pragma unroll
    for (int m = 0; m < 4; m++) {
#pragma unroll
        for (int r = 0; r < 4; r++) {
            int gm = bm + wr * 64 + m * 16 + (l >> 4) * 4 + r;
            if (gm >= M) continue;
#pragma unroll
            for (int n = 0; n < 4; n++) {
                int gn = bn + wc * 64 + n * 16 + lr;
                float vb = acc[m][n][r] + bias[gn];
                if (MODE == 1) {
                    float gl = 0.5f * vb * (1.0f + erff(vb * 0.70710678118f));
                    ((unsigned short*)Cout)[(size_t)gm * N + gn] = f2bf(gl);
                } else {
                    ((float*)Cout)[(size_t)gm * N + gn] = vb + res[(size_t)gm * N + gn];
                }
            }
        }
    }
}

// ---------------- classifier head ----------------
__global__ __launch_bounds__(256) void head_kernel(const float* __restrict__ x,
                                                   const float* __restrict__ Wh,
                                                   const float* __restrict__ bh,
                                                   float* __restrict__ logits) {
    __shared__ float xs[768];
    int b = blockIdx.x;
    int tid = threadIdx.x;
#pragma unroll
    for (int i = 0; i < 3; i++) xs[tid + i * 256] = x[(size_t)b * SEQ * DIM + tid + i * 256];
    __syncthreads();
    int wave = tid >> 6, lane = tid & 63;
    int o = blockIdx.y * 4 + wave;
    if (o < NOUT) {
        float acc = 0;
#pragma unroll
        for (int t = 0; t < 12; t++) {
            int d = lane + t * 64;
            acc = fmaf(xs[d], Wh[(size_t)o * DIM + d], acc);
        }
#pragma unroll
        for (int off = 32; off > 0; off >>= 1) acc += __shfl_down(acc, off, 64);
        if (lane == 0) logits[b * NOUT + o] = acc + bh[o];
    }
}

__global__ __launch_bounds__(256) void softmax_kernel(const float* __restrict__ logits,
                                                      float* __restrict__ out) {
    __shared__ float tmp[4];
    int b = blockIdx.x, tid = threadIdx.x;
    float vals[4];
    float mx = -1e30f;
#pragma unroll
    for (int i = 0; i < 4; i++) {
        int c = tid + i * 256;
        vals[i] = (c < NOUT) ? logits[b * NOUT + c] : -1e30f;
        mx = fmaxf(mx, vals[i]);
    }
#pragma unroll
    for (int o = 32; o > 0; o >>= 1) mx = fmaxf(mx, __shfl_down(mx, o, 64));
    int wave = tid >> 6, lane = tid & 63;
    __syncthreads();
    if (lane == 0) tmp[wave] = mx;
    __syncthreads();
    mx = fmaxf(fmaxf(tmp[0], tmp[1]), fmaxf(tmp[2], tmp[3]));
    float s = 0;
#pragma unroll
    for (int i = 0; i < 4; i++) {
        int c = tid + i * 256;
        if (c < NOUT) {
            vals[i] = __expf(vals[i] - mx);
            s += vals[i];
        } else vals[i] = 0.f;
    }
#pragma unroll
    for (int o = 32; o > 0; o >>= 1) s += __shfl_down(s, o, 64);
    __syncthreads();
    if (lane == 0) tmp[wave] = s;
    __syncthreads();
    s = tmp[0] + tmp[1] + tmp[2] + tmp[3];
    float invs = 1.0f / s;
#pragma unroll
    for (int i = 0; i < 4; i++) {
        int c = tid + i * 256;
        if (c < NOUT) out[b * NOUT + c] = vals[i] * invs;
    }
}

extern "C" void kernel_launch(void* const* d_in, const int* in_sizes, int n_in,
                              void* d_out, int out_size, void* d_ws, size_t ws_size,
                              hipStream_t stream) {
    const float* images = (const float*)d_in[0];
    const float* Wp   = (const float*)d_in[1];
    const float* bp   = (const float*)d_in[2];
    const float* cls  = (const float*)d_in[3];
    const float* pos  = (const float*)d_in[4];
    const float* ln1g = (const float*)d_in[5];
    const float* ln1b = (const float*)d_in[6];
    const float* Wq   = (const float*)d_in[7];
    const float* bq   = (const float*)d_in[8];
    const float* Wk   = (const float*)d_in[9];
    const float* bk   = (const float*)d_in[10];
    const float* Wv   = (const float*)d_in[11];
    const float* bv   = (const float*)d_in[12];
    const float* ln2g = (const float*)d_in[13];
    const float* ln2b = (const float*)d_in[14];
    const float* W1   = (const float*)d_in[15];
    const float* b1   = (const float*)d_in[16];
    const float* W2   = (const float*)d_in[17];
    const float* b2   = (const float*)d_in[18];
    const float* Wh   = (const float*)d_in[19];
    const float* bh   = (const float*)d_in[20];
    float* out = (float*)d_out;

    const size_t NX = (size_t)MROWS * DIM;          // 4,841,472
    float* ws = (float*)d_ws;
    float* x      = ws;
    float* h      = x + NX;
    float* logits = h + NX;
    unsigned short* hbf   = (unsigned short*)(logits + NBATCH * NOUT);
    unsigned short* h2bf  = hbf + NX;
    unsigned short* qb    = h2bf + NX;
    unsigned short* kb    = qb + NX;
    unsigned short* vb    = kb + NX;
    unsigned short* mid   = vb + NX;                 // MROWS*MDIM = 19,365,888
    unsigned short* wl1   = mid + (size_t)MROWS * MDIM;
    unsigned short* wl2   = wl1 + (size_t)MDIM * DIM;
    unsigned short* wqkvb = wl2 + (size_t)MDIM * DIM;

    cls_pos_kernel<<<dim3(NBATCH), dim3(256), 0, stream>>>(cls, pos, x);
    gemm_patch<<<dim3(49, 6), dim3(256), 0, stream>>>(images, Wp, bp, pos, x);
    cvt_qkvw<<<dim3(1024), dim3(256), 0, stream>>>(Wq, Wk, Wv, wqkvb);

    for (int l = 0; l < NLAYER; l++) {
        cvt4<<<dim3(1024), dim3(256), 0, stream>>>(W1 + (size_t)l * MDIM * DIM, wl1, MDIM * DIM / 4);
        cvt4<<<dim3(1024), dim3(256), 0, stream>>>(W2 + (size_t)l * MDIM * DIM, wl2, MDIM * DIM / 4);
        ln_wave<0><<<dim3(MROWS / 4), dim3(256), 0, stream>>>(
            x, nullptr, nullptr, hbf, ln1g + l * DIM, ln1b + l * DIM);
        qkv_mfma<<<dim3(50, 12), dim3(256), 0, stream>>>(
            hbf, wqkvb + (size_t)l * NHEAD * 12288,
            bq + l * NHEAD * DH, bk + l * NHEAD * DH, bv + l * NHEAD * DH,
            qb, kb, vb);
        attn_mfma<<<dim3(NBATCH, NHEAD), dim3(256), 0, stream>>>(qb, kb, vb, h);
        ln_wave<1><<<dim3(MROWS / 4), dim3(256), 0, stream>>>(
            x, h, x, h2bf, ln2g + l * DIM, ln2b + l * DIM);
        gemm_bf<1><<<dim3(50, 24), dim3(256), 0, stream>>>(
            h2bf, wl1, b1 + l * MDIM, mid, nullptr, MROWS, MDIM, DIM);
        gemm_bf<2><<<dim3(50, 6), dim3(256), 0, stream>>>(
            mid, wl2, b2 + l * DIM, x, x, MROWS, DIM, MDIM);
    }

    head_kernel<<<dim3(NBATCH, 250), dim3(256), 0, stream>>>(x, Wh, bh, logits);
    softmax_kernel<<<dim3(NBATCH), dim3(256), 0, stream>>>(logits, out);
}

// Round 3
// 3049.543 us; speedup vs baseline: 7.1286x; 1.0125x over previous
//
#include <hip/hip_runtime.h>
#include <math.h>
#include <stdint.h>

#define NBATCH 32
#define SEQ 197
#define DIM 768
#define NHEAD 12
#define DH 64
#define MDIM 3072
#define NLAYER 12
#define NPATCH 196
#define NOUT 1000
#define MROWS (NBATCH * SEQ)   // 6304

typedef __bf16 bf16x8 __attribute__((ext_vector_type(8)));
typedef float f32x4 __attribute__((ext_vector_type(4)));

__device__ __forceinline__ unsigned short f2bf(float f) {
    unsigned u = __float_as_uint(f);
    unsigned r = u + 0x7fffu + ((u >> 16) & 1u);
    return (unsigned short)(r >> 16);
}

__device__ __forceinline__ f32x4 mfma16(bf16x8 a, bf16x8 b, f32x4 c) {
    return __builtin_amdgcn_mfma_f32_16x16x32_bf16(a, b, c, 0, 0, 0);
}

// async global->LDS 16B: lds pointer wave-uniform base; HW writes lane l at base + l*16.
// global source address IS per-lane.
__device__ __forceinline__ void gload_lds16(const void* g, const void* lds) {
    __builtin_amdgcn_global_load_lds(
        (const __attribute__((address_space(1))) void*)(uintptr_t)g,
        (__attribute__((address_space(3))) void*)(uint32_t)(uintptr_t)lds,
        16, 0, 0);
}

// ---------------- fp32 -> bf16 converter (grid-stride) ----------------
__global__ __launch_bounds__(256) void cvt4(const float* __restrict__ src,
                                            unsigned short* __restrict__ dst, int n4) {
    int stride = gridDim.x * 256;
    for (int i = blockIdx.x * 256 + threadIdx.x; i < n4; i += stride) {
        float4 f = *(const float4*)(src + (size_t)i * 4);
        ushort4 o;
        o.x = f2bf(f.x); o.y = f2bf(f.y); o.z = f2bf(f.z); o.w = f2bf(f.w);
        *(ushort4*)(dst + (size_t)i * 4) = o;
    }
}

// gather Wq/Wk/Wv [L][H][e][d] -> wqkvb [L][H][3*64 rows][64] bf16
__global__ __launch_bounds__(256) void cvt_qkvw(const float* __restrict__ Wq,
                                                const float* __restrict__ Wk,
                                                const float* __restrict__ Wv,
                                                unsigned short* __restrict__ dst) {
    const int n = NLAYER * NHEAD * 3 * 64 * 64;
    int stride = gridDim.x * 256;
    for (int i = blockIdx.x * 256 + threadIdx.x; i < n; i += stride) {
        int d = i & 63, e = (i >> 6) & 63;
        int v = i >> 12;
        int t = v % 3, hh = (v / 3) % NHEAD, l = v / (3 * NHEAD);
        const float* src = (t == 0) ? Wq : (t == 1) ? Wk : Wv;
        dst[i] = f2bf(src[(((size_t)(l * NHEAD + hh)) * 64 + e) * 64 + d]);
    }
}

// ---------------- cls + pos init ----------------
__global__ __launch_bounds__(256) void cls_pos_kernel(const float* __restrict__ cls,
                                                      const float* __restrict__ pos,
                                                      float* __restrict__ x) {
    int b = blockIdx.x, tid = threadIdx.x;
#pragma unroll
    for (int i = 0; i < 3; i++) {
        int c = tid + i * 256;
        x[(size_t)b * SEQ * DIM + c] = cls[c] + pos[c];
    }
}

// ---------------- patch-embed GEMM: bf16 MFMA, gathered A (m97 structure) ----------------
// M = 6272 (=49*128 exact), N = 768, K = 768. k decodes as (c, i, j): k = c*256 + i*16 + j.
__global__ __launch_bounds__(256) void gemm_patch_bf(const unsigned short* __restrict__ imgbf,
                                                     const unsigned short* __restrict__ wpbf,
                                                     const float* __restrict__ bp,
                                                     const float* __restrict__ pos,
                                                     float* __restrict__ x) {
    __shared__ __align__(16) unsigned short As[128 * 32];
    __shared__ __align__(16) unsigned short Bs[128 * 32];
    const int t = threadIdx.x, l = t & 63, w = t >> 6;
    const int bm = blockIdx.x * 128, bn = blockIdx.y * 128;
    const int wr = w >> 1, wc = w & 1;
    f32x4 acc[4][4] = {};

    const int ra0 = t >> 2, ka0 = (t & 3) * 8;
    const int ra1 = (t + 256) >> 2, ka1 = ((t + 256) & 3) * 8;
    // decode patch rows (always valid: M = 6272)
    int gm0 = bm + ra0, b0 = gm0 / NPATCH, p0 = gm0 % NPATCH;
    int gm1 = bm + ra1, b1 = gm1 / NPATCH, p1 = gm1 % NPATCH;
    const unsigned short* ib0 =
        imgbf + ((size_t)b0 * 3 * 224 + (size_t)(p0 / 14) * 16) * 224 + (p0 % 14) * 16;
    const unsigned short* ib1 =
        imgbf + ((size_t)b1 * 3 * 224 + (size_t)(p1 / 14) * 16) * 224 + (p1 % 14) * 16;
    const unsigned short* Br0 = wpbf + (size_t)(bn + ra0) * 768 + ka0;
    const unsigned short* Br1 = wpbf + (size_t)(bn + ra1) * 768 + ka1;
    unsigned short* lA0 = As + (size_t)(0 * 256 + w * 64) * 8;
    unsigned short* lA1 = As + (size_t)(1 * 256 + w * 64) * 8;
    unsigned short* lB0 = Bs + (size_t)(0 * 256 + w * 64) * 8;
    unsigned short* lB1 = Bs + (size_t)(1 * 256 + w * 64) * 8;
    const int lr = l & 15, lk = (l >> 4) * 8;

    for (int k0 = 0; k0 < 768; k0 += 32) {
        int kA0 = k0 + ka0, kA1 = k0 + ka1;
        int c0 = kA0 >> 8, i0 = (kA0 >> 4) & 15, j0 = kA0 & 15;
        int c1 = kA1 >> 8, i1 = (kA1 >> 4) & 15, j1 = kA1 & 15;
        __syncthreads();
        gload_lds16(ib0 + ((size_t)c0 * 224 + i0) * 224 + j0, lA0);
        gload_lds16(ib1 + ((size_t)c1 * 224 + i1) * 224 + j1, lA1);
        gload_lds16(Br0 + k0, lB0);
        gload_lds16(Br1 + k0, lB1);
        __syncthreads();
        bf16x8 a[4], bfr[4];
#pragma unroll
        for (int m = 0; m < 4; m++)
            a[m] = *(const bf16x8*)(As + (wr * 64 + m * 16 + lr) * 32 + lk);
#pragma unroll
        for (int n = 0; n < 4; n++)
            bfr[n] = *(const bf16x8*)(Bs + (wc * 64 + n * 16 + lr) * 32 + lk);
#pragma unroll
        for (int m = 0; m < 4; m++)
#pragma unroll
            for (int n = 0; n < 4; n++)
                acc[m][n] = mfma16(a[m], bfr[n], acc[m][n]);
    }

#pragma unroll
    for (int m = 0; m < 4; m++) {
#pragma unroll
        for (int r = 0; r < 4; r++) {
            int gm = bm + wr * 64 + m * 16 + (l >> 4) * 4 + r;
            int b2 = gm / NPATCH, p2 = gm % NPATCH;
            size_t orow = (size_t)(b2 * SEQ + 1 + p2) * DIM;
#pragma unroll
            for (int n = 0; n < 4; n++) {
                int gn = bn + wc * 64 + n * 16 + lr;
                x[orow + gn] = acc[m][n][r] + bp[gn] + pos[(size_t)(1 + p2) * DIM + gn];
            }
        }
    }
}

// ---------------- wave-per-row LayerNorm, bf16 h out, optional residual ----------------
template <int RES>
__global__ __launch_bounds__(256) void ln_wave(const float* __restrict__ x_in,
                                               const float* __restrict__ addv,
                                               float* __restrict__ x_out,
                                               unsigned short* __restrict__ h_out,
                                               const float* __restrict__ g,
                                               const float* __restrict__ bb) {
    int w = threadIdx.x >> 6, l = threadIdx.x & 63;
    size_t row = (size_t)blockIdx.x * 4 + w;
    const float* xr = x_in + row * DIM;
    float4 v[3];
    float s = 0.f;
#pragma unroll
    for (int u = 0; u < 3; u++) {
        int c = u * 256 + l * 4;
        v[u] = *(const float4*)(xr + c);
        if (RES) {
            float4 a4 = *(const float4*)(addv + row * DIM + c);
            v[u].x += a4.x; v[u].y += a4.y; v[u].z += a4.z; v[u].w += a4.w;
        }
        s += v[u].x + v[u].y + v[u].z + v[u].w;
    }
#pragma unroll
    for (int o = 1; o < 64; o <<= 1) s += __shfl_xor(s, o, 64);
    float mean = s * (1.0f / 768.0f);
    float s2 = 0.f;
#pragma unroll
    for (int u = 0; u < 3; u++) {
        float dx = v[u].x - mean, dy = v[u].y - mean, dz = v[u].z - mean, dw = v[u].w - mean;
        s2 += dx * dx + dy * dy + dz * dz + dw * dw;
    }
#pragma unroll
    for (int o = 1; o < 64; o <<= 1) s2 += __shfl_xor(s2, o, 64);
    float inv = rsqrtf(s2 * (1.0f / 768.0f) + 1e-5f);
#pragma unroll
    for (int u = 0; u < 3; u++) {
        int c = u * 256 + l * 4;
        float4 g4 = *(const float4*)(g + c);
        float4 b4 = *(const float4*)(bb + c);
        ushort4 o;
        o.x = f2bf((v[u].x - mean) * inv * g4.x + b4.x);
        o.y = f2bf((v[u].y - mean) * inv * g4.y + b4.y);
        o.z = f2bf((v[u].z - mean) * inv * g4.z + b4.z);
        o.w = f2bf((v[u].w - mean) * inv * g4.w + b4.w);
        *(ushort4*)(h_out + row * DIM + c) = o;
        if (RES) *(float4*)(x_out + row * DIM + c) = v[u];
    }
}

// ---------------- QKV projection: per-head MFMA, K=64 ----------------
__global__ __launch_bounds__(256) void qkv_mfma(const unsigned short* __restrict__ hbf,
                                                const unsigned short* __restrict__ wqkv,
                                                const float* __restrict__ bq,
                                                const float* __restrict__ bk,
                                                const float* __restrict__ bv,
                                                unsigned short* __restrict__ q,
                                                unsigned short* __restrict__ k,
                                                unsigned short* __restrict__ v) {
    __shared__ __align__(16) unsigned short As[2 * 128 * 32];
    __shared__ __align__(16) unsigned short Bs[2 * 192 * 32];
    const int bm = blockIdx.x * 128, hd = blockIdx.y;
    const int t = threadIdx.x, l = t & 63, w = t >> 6;
    const unsigned short* wh = wqkv + (size_t)hd * 12288;

#pragma unroll
    for (int i = 0; i < 4; i++) {
        int p = t + i * 256;
        int kt = p >> 9, r = (p >> 2) & 127, kc = p & 3;
        int grow = min(bm + r, MROWS - 1);
        gload_lds16(hbf + (size_t)grow * DIM + hd * 64 + kt * 32 + kc * 8,
                    As + (size_t)(i * 256 + w * 64) * 8);
    }
#pragma unroll
    for (int i = 0; i < 6; i++) {
        int p = t + i * 256;
        int kt = p / 768, rem = p - kt * 768;
        int r = rem >> 2, kc = rem & 3;
        gload_lds16(wh + (size_t)r * 64 + kt * 32 + kc * 8,
                    Bs + (size_t)(i * 256 + w * 64) * 8);
    }
    __syncthreads();

    f32x4 acc[4][6] = {};
    const int wr = w >> 1, wc = w & 1;
    const int lr = l & 15, lk = (l >> 4) * 8;
#pragma unroll
    for (int ks = 0; ks < 2; ks++) {
        bf16x8 a[4], bfr[6];
#pragma unroll
        for (int m = 0; m < 4; m++)
            a[m] = *(const bf16x8*)(As + ks * 4096 + (wr * 64 + m * 16 + lr) * 32 + lk);
#pragma unroll
        for (int n = 0; n < 6; n++)
            bfr[n] = *(const bf16x8*)(Bs + ks * 6144 + (wc * 96 + n * 16 + lr) * 32 + lk);
#pragma unroll
        for (int m = 0; m < 4; m++)
#pragma unroll
            for (int n = 0; n < 6; n++)
                acc[m][n] = mfma16(a[m], bfr[n], acc[m][n]);
    }
#pragma unroll
    for (int n = 0; n < 6; n++) {
        int c = wc * 96 + n * 16 + lr;
        int tt = c >> 6, e = c & 63;
        const float* bias = (tt == 0) ? bq : (tt == 1) ? bk : bv;
        unsigned short* outp = (tt == 0) ? q : (tt == 1) ? k : v;
        float bval = bias[hd * 64 + e];
#pragma unroll
        for (int m = 0; m < 4; m++) {
#pragma unroll
            for (int r = 0; r < 4; r++) {
                int gm = bm + wr * 64 + m * 16 + (l >> 4) * 4 + r;
                if (gm < MROWS) outp[(size_t)gm * DIM + hd * 64 + e] = f2bf(acc[m][n][r] + bval);
            }
        }
    }
}

// ---------------- fused attention: MFMA, swapped QK^T, per-wave P in LDS ----------------
__global__ __launch_bounds__(256) void attn_mfma(const unsigned short* __restrict__ qg,
                                                 const unsigned short* __restrict__ kg,
                                                 const unsigned short* __restrict__ vg,
                                                 float* __restrict__ o) {
    __shared__ __align__(16) unsigned short Vt[64][232];   // V transposed [d][j], pad to 232
    __shared__ __align__(16) unsigned short P[4][16][232]; // per-wave P [q][j]
    const int b = blockIdx.x, hd = blockIdx.y;
    const int t = threadIdx.x, l = t & 63, w = t >> 6;
    const size_t base = ((size_t)b * SEQ) * DIM + hd * DH;

    for (int idx = t; idx < 224 * 16; idx += 256) {
        int j = idx >> 4, dg = idx & 15;
        if (j < SEQ) {
            ushort4 v4 = *(const ushort4*)(vg + base + (size_t)j * DIM + dg * 4);
            Vt[dg * 4 + 0][j] = v4.x; Vt[dg * 4 + 1][j] = v4.y;
            Vt[dg * 4 + 2][j] = v4.z; Vt[dg * 4 + 3][j] = v4.w;
        } else {
            Vt[dg * 4 + 0][j] = 0; Vt[dg * 4 + 1][j] = 0;
            Vt[dg * 4 + 2][j] = 0; Vt[dg * 4 + 3][j] = 0;
        }
    }
    {   // zero this wave's P padding cols 208..223
        int qq = l & 15, jj = 208 + (l >> 4) * 4;
        P[w][qq][jj] = 0; P[w][qq][jj + 1] = 0; P[w][qq][jj + 2] = 0; P[w][qq][jj + 3] = 0;
    }
    __syncthreads();

    const int lr = l & 15, lk4 = (l >> 4);
    for (int qt = w; qt < 13; qt += 4) {
        int qrow = min(qt * 16 + lr, SEQ - 1);
        const unsigned short* qp = qg + base + (size_t)qrow * DIM + lk4 * 8;
        bf16x8 q0 = *(const bf16x8*)qp;
        bf16x8 q1 = *(const bf16x8*)(qp + 32);
        f32x4 st[13];
#pragma unroll
        for (int jt = 0; jt < 13; jt++) st[jt] = (f32x4){0.f, 0.f, 0.f, 0.f};
#pragma unroll
        for (int jt = 0; jt < 13; jt++) {
            int jrow = min(jt * 16 + lr, SEQ - 1);
            const unsigned short* kp = kg + base + (size_t)jrow * DIM + lk4 * 8;
            bf16x8 k0 = *(const bf16x8*)kp;
            bf16x8 k1 = *(const bf16x8*)(kp + 32);
            st[jt] = mfma16(k0, q0, st[jt]);   // S^T[j][q]
            st[jt] = mfma16(k1, q1, st[jt]);
        }
        float mx = -1e30f;
#pragma unroll
        for (int jt = 0; jt < 13; jt++)
#pragma unroll
            for (int r = 0; r < 4; r++) {
                int j = jt * 16 + lk4 * 4 + r;
                float sv = st[jt][r] * 0.125f;
                st[jt][r] = (j < SEQ) ? sv : -1e30f;
                mx = fmaxf(mx, st[jt][r]);
            }
        mx = fmaxf(mx, __shfl_xor(mx, 16, 64));
        mx = fmaxf(mx, __shfl_xor(mx, 32, 64));
        float sum = 0.f;
#pragma unroll
        for (int jt = 0; jt < 13; jt++)
#pragma unroll
            for (int r = 0; r < 4; r++) {
                float p = __expf(st[jt][r] - mx);
                st[jt][r] = p;
                sum += p;
            }
        sum += __shfl_xor(sum, 16, 64);
        sum += __shfl_xor(sum, 32, 64);
        float inv = 1.0f / sum;
#pragma unroll
        for (int jt = 0; jt < 13; jt++) {
            ushort4 pk;
            pk.x = f2bf(st[jt][0] * inv); pk.y = f2bf(st[jt][1] * inv);
            pk.z = f2bf(st[jt][2] * inv); pk.w = f2bf(st[jt][3] * inv);
            *(ushort4*)&P[w][lr][jt * 16 + lk4 * 4] = pk;
        }
        f32x4 acc[4] = {};
#pragma unroll
        for (int kt = 0; kt < 7; kt++) {
            bf16x8 pa = *(const bf16x8*)&P[w][lr][kt * 32 + lk4 * 8];
#pragma unroll
            for (int nt = 0; nt < 4; nt++) {
                bf16x8 bv = *(const bf16x8*)&Vt[nt * 16 + lr][kt * 32 + lk4 * 8];
                acc[nt] = mfma16(pa, bv, acc[nt]);
            }
        }
#pragma unroll
        for (int nt = 0; nt < 4; nt++)
#pragma unroll
            for (int r = 0; r < 4; r++) {
                int qq = qt * 16 + lk4 * 4 + r;
                if (qq < SEQ) o[base + (size_t)qq * DIM + nt * 16 + lr] = acc[nt][r];
            }
    }
}

// ---------------- bf16 MFMA NT GEMM, 128x128 tile, BK=32 (m97 structure) ----------------
// MODE 1: gelu(acc+bias) -> bf16 C ; MODE 2: acc+bias+res -> fp32 C
template <int MODE>
__global__ __launch_bounds__(256) void gemm_bf(const unsigned short* __restrict__ A,
                                               const unsigned short* __restrict__ Bw,
                                               const float* __restrict__ bias,
                                               void* __restrict__ Cout,
                                               const float* __restrict__ res,
                                               int M, int N, int K) {
    __shared__ __align__(16) unsigned short As[128 * 32];
    __shared__ __align__(16) unsigned short Bs[128 * 32];
    const int t = threadIdx.x, l = t & 63, w = t >> 6;
    const int bm = blockIdx.x * 128, bn = blockIdx.y * 128;
    const int wr = w >> 1, wc = w & 1;
    f32x4 acc[4][4] = {};

    const int ra0 = t >> 2, ka0 = (t & 3) * 8;
    const int ra1 = (t + 256) >> 2, ka1 = ((t + 256) & 3) * 8;
    const unsigned short* Ar0 = A + (size_t)min(bm + ra0, M - 1) * K + ka0;
    const unsigned short* Ar1 = A + (size_t)min(bm + ra1, M - 1) * K + ka1;
    const unsigned short* Br0 = Bw + (size_t)(bn + ra0) * K + ka0;
    const unsigned short* Br1 = Bw + (size_t)(bn + ra1) * K + ka1;
    unsigned short* lA0 = As + (size_t)(0 * 256 + w * 64) * 8;
    unsigned short* lA1 = As + (size_t)(1 * 256 + w * 64) * 8;
    unsigned short* lB0 = Bs + (size_t)(0 * 256 + w * 64) * 8;
    unsigned short* lB1 = Bs + (size_t)(1 * 256 + w * 64) * 8;
    const int lr = l & 15, lk = (l >> 4) * 8;

    for (int k0 = 0; k0 < K; k0 += 32) {
        __syncthreads();
        gload_lds16(Ar0 + k0, lA0);
        gload_lds16(Ar1 + k0, lA1);
        gload_lds16(Br0 + k0, lB0);
        gload_lds16(Br1 + k0, lB1);
        __syncthreads();
        bf16x8 a[4], bfr[4];
#pragma unroll
        for (int m = 0; m < 4; m++)
            a[m] = *(const bf16x8*)(As + (wr * 64 + m * 16 + lr) * 32 + lk);
#pragma unroll
        for (int n = 0; n < 4; n++)
            bfr[n] = *(const bf16x8*)(Bs + (wc * 64 + n * 16 + lr) * 32 + lk);
#pragma unroll
        for (int m = 0; m < 4; m++)
#pragma unroll
            for (int n = 0; n < 4; n++)
                acc[m][n] = mfma16(a[m], bfr[n], acc[m][n]);
    }

#pragma unroll
    for (int m = 0; m < 4; m++) {
#pragma unroll
        for (int r = 0; r < 4; r++) {
            int gm = bm + wr * 64 + m * 16 + (l >> 4) * 4 + r;
            if (gm >= M) continue;
#pragma unroll
            for (int n = 0; n < 4; n++) {
                int gn = bn + wc * 64 + n * 16 + lr;
                float vb = acc[m][n][r] + bias[gn];
                if (MODE == 1) {
                    float gl = 0.5f * vb * (1.0f + erff(vb * 0.70710678118f));
                    ((unsigned short*)Cout)[(size_t)gm * N + gn] = f2bf(gl);
                } else {
                    ((float*)Cout)[(size_t)gm * N + gn] = vb + res[(size_t)gm * N + gn];
                }
            }
        }
    }
}

// ---------------- classifier head ----------------
__global__ __launch_bounds__(256) void head_kernel(const float* __restrict__ x,
                                                   const float* __restrict__ Wh,
                                                   const float* __restrict__ bh,
                                                   float* __restrict__ logits) {
    __shared__ float xs[768];
    int b = blockIdx.x;
    int tid = threadIdx.x;
#pragma unroll
    for (int i = 0; i < 3; i++) xs[tid + i * 256] = x[(size_t)b * SEQ * DIM + tid + i * 256];
    __syncthreads();
    int wave = tid >> 6, lane = tid & 63;
    int o = blockIdx.y * 4 + wave;
    if (o < NOUT) {
        float acc = 0;
#pragma unroll
        for (int t = 0; t < 12; t++) {
            int d = lane + t * 64;
            acc = fmaf(xs[d], Wh[(size_t)o * DIM + d], acc);
        }
#pragma unroll
        for (int off = 32; off > 0; off >>= 1) acc += __shfl_down(acc, off, 64);
        if (lane == 0) logits[b * NOUT + o] = acc + bh[o];
    }
}

__global__ __launch_bounds__(256) void softmax_kernel(const float* __restrict__ logits,
                                                      float* __restrict__ out) {
    __shared__ float tmp[4];
    int b = blockIdx.x, tid = threadIdx.x;
    float vals[4];
    float mx = -1e30f;
#pragma unroll
    for (int i = 0; i < 4; i++) {
        int c = tid + i * 256;
        vals[i] = (c < NOUT) ? logits[b * NOUT + c] : -1e30f;
        mx = fmaxf(mx, vals[i]);
    }
#pragma unroll
    for (int o = 32; o > 0; o >>= 1) mx = fmaxf(mx, __shfl_down(mx, o, 64));
    int wave = tid >> 6, lane = tid & 63;
    __syncthreads();
    if (lane == 0) tmp[wave] = mx;
    __syncthreads();
    mx = fmaxf(fmaxf(tmp[0], tmp[1]), fmaxf(tmp[2], tmp[3]));
    float s = 0;
#pragma unroll
    for (int i = 0; i < 4; i++) {
        int c = tid + i * 256;
        if (c < NOUT) {
            vals[i] = __expf(vals[i] - mx);
            s += vals[i];
        } else vals[i] = 0.f;
    }
#pragma unroll
    for (int o = 32; o > 0; o >>= 1) s += __shfl_down(s, o, 64);
    __syncthreads();
    if (lane == 0) tmp[wave] = s;
    __syncthreads();
    s = tmp[0] + tmp[1] + tmp[2] + tmp[3];
    float invs = 1.0f / s;
#pragma unroll
    for (int i = 0; i < 4; i++) {
        int c = tid + i * 256;
        if (c < NOUT) out[b * NOUT + c] = vals[i] * invs;
    }
}

extern "C" void kernel_launch(void* const* d_in, const int* in_sizes, int n_in,
                              void* d_out, int out_size, void* d_ws, size_t ws_size,
                              hipStream_t stream) {
    const float* images = (const float*)d_in[0];
    const float* Wp   = (const float*)d_in[1];
    const float* bp   = (const float*)d_in[2];
    const float* cls  = (const float*)d_in[3];
    const float* pos  = (const float*)d_in[4];
    const float* ln1g = (const float*)d_in[5];
    const float* ln1b = (const float*)d_in[6];
    const float* Wq   = (const float*)d_in[7];
    const float* bq   = (const float*)d_in[8];
    const float* Wk   = (const float*)d_in[9];
    const float* bk   = (const float*)d_in[10];
    const float* Wv   = (const float*)d_in[11];
    const float* bv   = (const float*)d_in[12];
    const float* ln2g = (const float*)d_in[13];
    const float* ln2b = (const float*)d_in[14];
    const float* W1   = (const float*)d_in[15];
    const float* b1   = (const float*)d_in[16];
    const float* W2   = (const float*)d_in[17];
    const float* b2   = (const float*)d_in[18];
    const float* Wh   = (const float*)d_in[19];
    const float* bh   = (const float*)d_in[20];
    float* out = (float*)d_out;

    const size_t NX = (size_t)MROWS * DIM;            // 4,841,472
    const size_t NIMG = (size_t)NBATCH * 3 * 224 * 224; // 4,816,896
    const size_t NW = (size_t)MDIM * DIM;             // 2,359,296 per layer

    char* p = (char*)d_ws;
    float* x      = (float*)p;            p += NX * 4;
    float* h      = (float*)p;            p += NX * 4;
    float* logits = (float*)p;            p += (size_t)NBATCH * NOUT * 4;
    unsigned short* hbf   = (unsigned short*)p; p += NX * 2;
    unsigned short* h2bf  = (unsigned short*)p; p += NX * 2;
    unsigned short* qb    = (unsigned short*)p; p += NX * 2;
    unsigned short* kb    = (unsigned short*)p; p += NX * 2;
    unsigned short* vb    = (unsigned short*)p; p += NX * 2;
    unsigned short* mid   = (unsigned short*)p; p += (size_t)MROWS * MDIM * 2;
    unsigned short* wqkvb = (unsigned short*)p; p += (size_t)NLAYER * NHEAD * 12288 * 2;
    unsigned short* imgbf = (unsigned short*)p; p += NIMG * 2;
    unsigned short* wpbf  = (unsigned short*)p; p += (size_t)DIM * DIM * 2;
    size_t used_base = (size_t)(p - (char*)d_ws);
    // big path: all-layer W1/W2 pre-conversion (needs 113.2 MB more)
    bool big = ws_size >= used_base + (size_t)2 * NLAYER * NW * 2;
    unsigned short* w1a = (unsigned short*)p;
    unsigned short* w2a = big ? w1a + (size_t)NLAYER * NW : w1a + NW;

    cls_pos_kernel<<<dim3(NBATCH), dim3(256), 0, stream>>>(cls, pos, x);
    cvt4<<<dim3(2048), dim3(256), 0, stream>>>(images, imgbf, (int)(NIMG / 4));
    cvt4<<<dim3(576), dim3(256), 0, stream>>>(Wp, wpbf, (int)(DIM * DIM / 4));
    cvt_qkvw<<<dim3(1024), dim3(256), 0, stream>>>(Wq, Wk, Wv, wqkvb);
    gemm_patch_bf<<<dim3(49, 6), dim3(256), 0, stream>>>(imgbf, wpbf, bp, pos, x);
    if (big) {
        cvt4<<<dim3(2048), dim3(256), 0, stream>>>(W1, w1a, (int)(NLAYER * NW / 4));
        cvt4<<<dim3(2048), dim3(256), 0, stream>>>(W2, w2a, (int)(NLAYER * NW / 4));
    }

    for (int l = 0; l < NLAYER; l++) {
        const unsigned short* wl1 = big ? w1a + (size_t)l * NW : w1a;
        const unsigned short* wl2 = big ? w2a + (size_t)l * NW : w2a;
        if (!big) {
            cvt4<<<dim3(2048), dim3(256), 0, stream>>>(W1 + (size_t)l * NW, w1a, (int)(NW / 4));
            cvt4<<<dim3(2048), dim3(256), 0, stream>>>(W2 + (size_t)l * NW, w1a + NW, (int)(NW / 4));
        }
        ln_wave<0><<<dim3(MROWS / 4), dim3(256), 0, stream>>>(
            x, nullptr, nullptr, hbf, ln1g + l * DIM, ln1b + l * DIM);
        qkv_mfma<<<dim3(50, 12), dim3(256), 0, stream>>>(
            hbf, wqkvb + (size_t)l * NHEAD * 12288,
            bq + l * NHEAD * DH, bk + l * NHEAD * DH, bv + l * NHEAD * DH,
            qb, kb, vb);
        attn_mfma<<<dim3(NBATCH, NHEAD), dim3(256), 0, stream>>>(qb, kb, vb, h);
        ln_wave<1><<<dim3(MROWS / 4), dim3(256), 0, stream>>>(
            x, h, x, h2bf, ln2g + l * DIM, ln2b + l * DIM);
        gemm_bf<1><<<dim3(50, 24), dim3(256), 0, stream>>>(
            h2bf, wl1, b1 + l * MDIM, mid, nullptr, MROWS, MDIM, DIM);
        gemm_bf<2><<<dim3(50, 6), dim3(256), 0, stream>>>(
            mid, wl2, b2 + l * DIM, x, x, MROWS, DIM, MDIM);
    }

    head_kernel<<<dim3(NBATCH, 250), dim3(256), 0, stream>>>(x, Wh, bh, logits);
    softmax_kernel<<<dim3(NBATCH), dim3(256), 0, stream>>>(logits, out);
}

// Round 4
// 2837.826 us; speedup vs baseline: 7.6605x; 1.0746x over previous
//
#include <hip/hip_runtime.h>
#include <math.h>
#include <stdint.h>

#define NBATCH 32
#define SEQ 197
#define DIM 768
#define NHEAD 12
#define DH 64
#define MDIM 3072
#define NLAYER 12
#define NPATCH 196
#define NOUT 1000
#define MROWS (NBATCH * SEQ)   // 6304

typedef __bf16 bf16x8 __attribute__((ext_vector_type(8)));
typedef float f32x4 __attribute__((ext_vector_type(4)));

__device__ __forceinline__ unsigned short f2bf(float f) {
    unsigned u = __float_as_uint(f);
    unsigned r = u + 0x7fffu + ((u >> 16) & 1u);
    return (unsigned short)(r >> 16);
}

__device__ __forceinline__ f32x4 mfma16(bf16x8 a, bf16x8 b, f32x4 c) {
    return __builtin_amdgcn_mfma_f32_16x16x32_bf16(a, b, c, 0, 0, 0);
}

// async global->LDS 16B: lds pointer wave-uniform base; HW writes lane l at base + l*16.
__device__ __forceinline__ void gload_lds16(const void* g, const void* lds) {
    __builtin_amdgcn_global_load_lds(
        (const __attribute__((address_space(1))) void*)(uintptr_t)g,
        (__attribute__((address_space(3))) void*)(uint32_t)(uintptr_t)lds,
        16, 0, 0);
}

// ---------------- fp32 -> bf16 converter (grid-stride) ----------------
__global__ __launch_bounds__(256) void cvt4(const float* __restrict__ src,
                                            unsigned short* __restrict__ dst, int n4) {
    int stride = gridDim.x * 256;
    for (int i = blockIdx.x * 256 + threadIdx.x; i < n4; i += stride) {
        float4 f = *(const float4*)(src + (size_t)i * 4);
        ushort4 o;
        o.x = f2bf(f.x); o.y = f2bf(f.y); o.z = f2bf(f.z); o.w = f2bf(f.w);
        *(ushort4*)(dst + (size_t)i * 4) = o;
    }
}

// gather Wq/Wk/Wv [L][H][e][d] -> wqkvb [L][H][3*64 rows][64] bf16
__global__ __launch_bounds__(256) void cvt_qkvw(const float* __restrict__ Wq,
                                                const float* __restrict__ Wk,
                                                const float* __restrict__ Wv,
                                                unsigned short* __restrict__ dst) {
    const int n = NLAYER * NHEAD * 3 * 64 * 64;
    int stride = gridDim.x * 256;
    for (int i = blockIdx.x * 256 + threadIdx.x; i < n; i += stride) {
        int d = i & 63, e = (i >> 6) & 63;
        int v = i >> 12;
        int t = v % 3, hh = (v / 3) % NHEAD, l = v / (3 * NHEAD);
        const float* src = (t == 0) ? Wq : (t == 1) ? Wk : Wv;
        dst[i] = f2bf(src[(((size_t)(l * NHEAD + hh)) * 64 + e) * 64 + d]);
    }
}

// ---------------- cls + pos init ----------------
__global__ __launch_bounds__(256) void cls_pos_kernel(const float* __restrict__ cls,
                                                      const float* __restrict__ pos,
                                                      float* __restrict__ x) {
    int b = blockIdx.x, tid = threadIdx.x;
#pragma unroll
    for (int i = 0; i < 3; i++) {
        int c = tid + i * 256;
        x[(size_t)b * SEQ * DIM + c] = cls[c] + pos[c];
    }
}

// ---------------- patch-embed GEMM: bf16 MFMA, gathered A, dbuf ----------------
__global__ __launch_bounds__(256) void gemm_patch_bf(const unsigned short* __restrict__ imgbf,
                                                     const unsigned short* __restrict__ wpbf,
                                                     const float* __restrict__ bp,
                                                     const float* __restrict__ pos,
                                                     float* __restrict__ x) {
    __shared__ __align__(16) unsigned short As[2][128 * 32];
    __shared__ __align__(16) unsigned short Bs[2][128 * 32];
    const int t = threadIdx.x, l = t & 63, w = t >> 6;
    const int bm = blockIdx.x * 128, bn = blockIdx.y * 128;
    const int wr = w >> 1, wc = w & 1;
    f32x4 acc[4][4] = {};

    const int ra0 = t >> 2, ka0 = (t & 3) * 8;
    const int ra1 = (t + 256) >> 2, ka1 = ((t + 256) & 3) * 8;
    int gm0 = bm + ra0, b0 = gm0 / NPATCH, p0 = gm0 % NPATCH;
    int gm1 = bm + ra1, b1 = gm1 / NPATCH, p1 = gm1 % NPATCH;
    const unsigned short* ib0 =
        imgbf + ((size_t)b0 * 3 * 224 + (size_t)(p0 / 14) * 16) * 224 + (p0 % 14) * 16;
    const unsigned short* ib1 =
        imgbf + ((size_t)b1 * 3 * 224 + (size_t)(p1 / 14) * 16) * 224 + (p1 % 14) * 16;
    const unsigned short* Br0 = wpbf + (size_t)(bn + ra0) * 768 + ka0;
    const unsigned short* Br1 = wpbf + (size_t)(bn + ra1) * 768 + ka1;
    const int lA0 = (0 * 256 + w * 64) * 8, lA1 = (1 * 256 + w * 64) * 8;
    const int lr = l & 15, lk = (l >> 4) * 8;

#define PATCH_STAGE(buf, k0)                                                   \
    {                                                                          \
        int kA0 = (k0) + ka0, kA1 = (k0) + ka1;                                \
        int c0 = kA0 >> 8, i0 = (kA0 >> 4) & 15, j0 = kA0 & 15;                \
        int c1 = kA1 >> 8, i1 = (kA1 >> 4) & 15, j1 = kA1 & 15;                \
        gload_lds16(ib0 + ((size_t)c0 * 224 + i0) * 224 + j0, As[buf] + lA0);  \
        gload_lds16(ib1 + ((size_t)c1 * 224 + i1) * 224 + j1, As[buf] + lA1);  \
        gload_lds16(Br0 + (k0), Bs[buf] + lA0);                                \
        gload_lds16(Br1 + (k0), Bs[buf] + lA1);                                \
    }

    PATCH_STAGE(0, 0);
    __syncthreads();
    int cur = 0;
    for (int k0 = 0; k0 < 768; k0 += 32) {
        if (k0 + 32 < 768) PATCH_STAGE(cur ^ 1, k0 + 32);
        bf16x8 a[4], bfr[4];
#pragma unroll
        for (int m = 0; m < 4; m++)
            a[m] = *(const bf16x8*)(As[cur] + (wr * 64 + m * 16 + lr) * 32 + lk);
#pragma unroll
        for (int n = 0; n < 4; n++)
            bfr[n] = *(const bf16x8*)(Bs[cur] + (wc * 64 + n * 16 + lr) * 32 + lk);
#pragma unroll
        for (int m = 0; m < 4; m++)
#pragma unroll
            for (int n = 0; n < 4; n++)
                acc[m][n] = mfma16(a[m], bfr[n], acc[m][n]);
        __syncthreads();
        cur ^= 1;
    }
#undef PATCH_STAGE

#pragma unroll
    for (int m = 0; m < 4; m++) {
#pragma unroll
        for (int r = 0; r < 4; r++) {
            int gm = bm + wr * 64 + m * 16 + (l >> 4) * 4 + r;
            int b2 = gm / NPATCH, p2 = gm % NPATCH;
            size_t orow = (size_t)(b2 * SEQ + 1 + p2) * DIM;
#pragma unroll
            for (int n = 0; n < 4; n++) {
                int gn = bn + wc * 64 + n * 16 + lr;
                x[orow + gn] = acc[m][n][r] + bp[gn] + pos[(size_t)(1 + p2) * DIM + gn];
            }
        }
    }
}

// ---------------- wave-per-row LayerNorm, bf16 h out ----------------
// RES: v = x + addv, write x_out.  RED: v = x + badd + sum(4 partials), write x_out.
template <int RES, int RED>
__global__ __launch_bounds__(256) void ln_wave(const float* __restrict__ x_in,
                                               const float* __restrict__ addv,
                                               float* __restrict__ x_out,
                                               unsigned short* __restrict__ h_out,
                                               const float* __restrict__ g,
                                               const float* __restrict__ bb,
                                               const float* __restrict__ parts,
                                               const float* __restrict__ badd) {
    int w = threadIdx.x >> 6, l = threadIdx.x & 63;
    size_t row = (size_t)blockIdx.x * 4 + w;
    const float* xr = x_in + row * DIM;
    float4 v[3];
    float s = 0.f;
#pragma unroll
    for (int u = 0; u < 3; u++) {
        int c = u * 256 + l * 4;
        v[u] = *(const float4*)(xr + c);
        if (RES) {
            float4 a4 = *(const float4*)(addv + row * DIM + c);
            v[u].x += a4.x; v[u].y += a4.y; v[u].z += a4.z; v[u].w += a4.w;
        }
        if (RED) {
            float4 b4 = *(const float4*)(badd + c);
            v[u].x += b4.x; v[u].y += b4.y; v[u].z += b4.z; v[u].w += b4.w;
#pragma unroll
            for (int kc = 0; kc < 4; kc++) {
                float4 p4 = *(const float4*)(parts + ((size_t)kc * MROWS + row) * DIM + c);
                v[u].x += p4.x; v[u].y += p4.y; v[u].z += p4.z; v[u].w += p4.w;
            }
        }
        s += v[u].x + v[u].y + v[u].z + v[u].w;
    }
#pragma unroll
    for (int o = 1; o < 64; o <<= 1) s += __shfl_xor(s, o, 64);
    float mean = s * (1.0f / 768.0f);
    float s2 = 0.f;
#pragma unroll
    for (int u = 0; u < 3; u++) {
        float dx = v[u].x - mean, dy = v[u].y - mean, dz = v[u].z - mean, dw = v[u].w - mean;
        s2 += dx * dx + dy * dy + dz * dz + dw * dw;
    }
#pragma unroll
    for (int o = 1; o < 64; o <<= 1) s2 += __shfl_xor(s2, o, 64);
    float inv = rsqrtf(s2 * (1.0f / 768.0f) + 1e-5f);
#pragma unroll
    for (int u = 0; u < 3; u++) {
        int c = u * 256 + l * 4;
        float4 g4 = *(const float4*)(g + c);
        float4 b4 = *(const float4*)(bb + c);
        ushort4 o;
        o.x = f2bf((v[u].x - mean) * inv * g4.x + b4.x);
        o.y = f2bf((v[u].y - mean) * inv * g4.y + b4.y);
        o.z = f2bf((v[u].z - mean) * inv * g4.z + b4.z);
        o.w = f2bf((v[u].w - mean) * inv * g4.w + b4.w);
        *(ushort4*)(h_out + row * DIM + c) = o;
        if (RES || RED) *(float4*)(x_out + row * DIM + c) = v[u];
    }
}

// ---------------- final split-K reduce: x += badd + sum(4 partials) ----------------
__global__ __launch_bounds__(256) void reduce4(float* __restrict__ x,
                                               const float* __restrict__ parts,
                                               const float* __restrict__ badd) {
    int w = threadIdx.x >> 6, l = threadIdx.x & 63;
    size_t row = (size_t)blockIdx.x * 4 + w;
#pragma unroll
    for (int u = 0; u < 3; u++) {
        int c = u * 256 + l * 4;
        float4 v = *(const float4*)(x + row * DIM + c);
        float4 b4 = *(const float4*)(badd + c);
        v.x += b4.x; v.y += b4.y; v.z += b4.z; v.w += b4.w;
#pragma unroll
        for (int kc = 0; kc < 4; kc++) {
            float4 p4 = *(const float4*)(parts + ((size_t)kc * MROWS + row) * DIM + c);
            v.x += p4.x; v.y += p4.y; v.z += p4.z; v.w += p4.w;
        }
        *(float4*)(x + row * DIM + c) = v;
    }
}

// ---------------- QKV projection: per-head MFMA, K=64 ----------------
__global__ __launch_bounds__(256) void qkv_mfma(const unsigned short* __restrict__ hbf,
                                                const unsigned short* __restrict__ wqkv,
                                                const float* __restrict__ bq,
                                                const float* __restrict__ bk,
                                                const float* __restrict__ bv,
                                                unsigned short* __restrict__ q,
                                                unsigned short* __restrict__ k,
                                                unsigned short* __restrict__ v) {
    __shared__ __align__(16) unsigned short As[2 * 128 * 32];
    __shared__ __align__(16) unsigned short Bs[2 * 192 * 32];
    const int bm = blockIdx.x * 128, hd = blockIdx.y;
    const int t = threadIdx.x, l = t & 63, w = t >> 6;
    const unsigned short* wh = wqkv + (size_t)hd * 12288;

#pragma unroll
    for (int i = 0; i < 4; i++) {
        int p = t + i * 256;
        int kt = p >> 9, r = (p >> 2) & 127, kc = p & 3;
        int grow = min(bm + r, MROWS - 1);
        gload_lds16(hbf + (size_t)grow * DIM + hd * 64 + kt * 32 + kc * 8,
                    As + (size_t)(i * 256 + w * 64) * 8);
    }
#pragma unroll
    for (int i = 0; i < 6; i++) {
        int p = t + i * 256;
        int kt = p / 768, rem = p - kt * 768;
        int r = rem >> 2, kc = rem & 3;
        gload_lds16(wh + (size_t)r * 64 + kt * 32 + kc * 8,
                    Bs + (size_t)(i * 256 + w * 64) * 8);
    }
    __syncthreads();

    f32x4 acc[4][6] = {};
    const int wr = w >> 1, wc = w & 1;
    const int lr = l & 15, lk = (l >> 4) * 8;
#pragma unroll
    for (int ks = 0; ks < 2; ks++) {
        bf16x8 a[4], bfr[6];
#pragma unroll
        for (int m = 0; m < 4; m++)
            a[m] = *(const bf16x8*)(As + ks * 4096 + (wr * 64 + m * 16 + lr) * 32 + lk);
#pragma unroll
        for (int n = 0; n < 6; n++)
            bfr[n] = *(const bf16x8*)(Bs + ks * 6144 + (wc * 96 + n * 16 + lr) * 32 + lk);
#pragma unroll
        for (int m = 0; m < 4; m++)
#pragma unroll
            for (int n = 0; n < 6; n++)
                acc[m][n] = mfma16(a[m], bfr[n], acc[m][n]);
    }
#pragma unroll
    for (int n = 0; n < 6; n++) {
        int c = wc * 96 + n * 16 + lr;
        int tt = c >> 6, e = c & 63;
        const float* bias = (tt == 0) ? bq : (tt == 1) ? bk : bv;
        unsigned short* outp = (tt == 0) ? q : (tt == 1) ? k : v;
        float bval = bias[hd * 64 + e];
#pragma unroll
        for (int m = 0; m < 4; m++) {
#pragma unroll
            for (int r = 0; r < 4; r++) {
                int gm = bm + wr * 64 + m * 16 + (l >> 4) * 4 + r;
                if (gm < MROWS) outp[(size_t)gm * DIM + hd * 64 + e] = f2bf(acc[m][n][r] + bval);
            }
        }
    }
}

// ---------------- fused attention: MFMA, swapped QK^T, per-wave P in LDS ----------------
__global__ __launch_bounds__(256) void attn_mfma(const unsigned short* __restrict__ qg,
                                                 const unsigned short* __restrict__ kg,
                                                 const unsigned short* __restrict__ vg,
                                                 float* __restrict__ o) {
    __shared__ __align__(16) unsigned short Vt[64][232];   // V transposed [d][j], pad to 232
    __shared__ __align__(16) unsigned short P[4][16][232]; // per-wave P [q][j]
    const int b = blockIdx.x, hd = blockIdx.y;
    const int t = threadIdx.x, l = t & 63, w = t >> 6;
    const size_t base = ((size_t)b * SEQ) * DIM + hd * DH;

    for (int idx = t; idx < 224 * 16; idx += 256) {
        int j = idx >> 4, dg = idx & 15;
        if (j < SEQ) {
            ushort4 v4 = *(const ushort4*)(vg + base + (size_t)j * DIM + dg * 4);
            Vt[dg * 4 + 0][j] = v4.x; Vt[dg * 4 + 1][j] = v4.y;
            Vt[dg * 4 + 2][j] = v4.z; Vt[dg * 4 + 3][j] = v4.w;
        } else {
            Vt[dg * 4 + 0][j] = 0; Vt[dg * 4 + 1][j] = 0;
            Vt[dg * 4 + 2][j] = 0; Vt[dg * 4 + 3][j] = 0;
        }
    }
    {
        int qq = l & 15, jj = 208 + (l >> 4) * 4;
        P[w][qq][jj] = 0; P[w][qq][jj + 1] = 0; P[w][qq][jj + 2] = 0; P[w][qq][jj + 3] = 0;
    }
    __syncthreads();

    const int lr = l & 15, lk4 = (l >> 4);
    for (int qt = w; qt < 13; qt += 4) {
        int qrow = min(qt * 16 + lr, SEQ - 1);
        const unsigned short* qp = qg + base + (size_t)qrow * DIM + lk4 * 8;
        bf16x8 q0 = *(const bf16x8*)qp;
        bf16x8 q1 = *(const bf16x8*)(qp + 32);
        f32x4 st[13];
#pragma unroll
        for (int jt = 0; jt < 13; jt++) st[jt] = (f32x4){0.f, 0.f, 0.f, 0.f};
#pragma unroll
        for (int jt = 0; jt < 13; jt++) {
            int jrow = min(jt * 16 + lr, SEQ - 1);
            const unsigned short* kp = kg + base + (size_t)jrow * DIM + lk4 * 8;
            bf16x8 k0 = *(const bf16x8*)kp;
            bf16x8 k1 = *(const bf16x8*)(kp + 32);
            st[jt] = mfma16(k0, q0, st[jt]);   // S^T[j][q]
            st[jt] = mfma16(k1, q1, st[jt]);
        }
        float mx = -1e30f;
#pragma unroll
        for (int jt = 0; jt < 13; jt++)
#pragma unroll
            for (int r = 0; r < 4; r++) {
                int j = jt * 16 + lk4 * 4 + r;
                float sv = st[jt][r] * 0.125f;
                st[jt][r] = (j < SEQ) ? sv : -1e30f;
                mx = fmaxf(mx, st[jt][r]);
            }
        mx = fmaxf(mx, __shfl_xor(mx, 16, 64));
        mx = fmaxf(mx, __shfl_xor(mx, 32, 64));
        float sum = 0.f;
#pragma unroll
        for (int jt = 0; jt < 13; jt++)
#pragma unroll
            for (int r = 0; r < 4; r++) {
                float p = __expf(st[jt][r] - mx);
                st[jt][r] = p;
                sum += p;
            }
        sum += __shfl_xor(sum, 16, 64);
        sum += __shfl_xor(sum, 32, 64);
        float inv = 1.0f / sum;
#pragma unroll
        for (int jt = 0; jt < 13; jt++) {
            ushort4 pk;
            pk.x = f2bf(st[jt][0] * inv); pk.y = f2bf(st[jt][1] * inv);
            pk.z = f2bf(st[jt][2] * inv); pk.w = f2bf(st[jt][3] * inv);
            *(ushort4*)&P[w][lr][jt * 16 + lk4 * 4] = pk;
        }
        f32x4 acc[4] = {};
#pragma unroll
        for (int kt = 0; kt < 7; kt++) {
            bf16x8 pa = *(const bf16x8*)&P[w][lr][kt * 32 + lk4 * 8];
#pragma unroll
            for (int nt = 0; nt < 4; nt++) {
                bf16x8 bv = *(const bf16x8*)&Vt[nt * 16 + lr][kt * 32 + lk4 * 8];
                acc[nt] = mfma16(pa, bv, acc[nt]);
            }
        }
#pragma unroll
        for (int nt = 0; nt < 4; nt++)
#pragma unroll
            for (int r = 0; r < 4; r++) {
                int qq = qt * 16 + lk4 * 4 + r;
                if (qq < SEQ) o[base + (size_t)qq * DIM + nt * 16 + lr] = acc[nt][r];
            }
    }
}

// ---------------- bf16 MFMA NT GEMM, 128x128 tile, dbuf 2-phase ----------------
// MODE 1: gelu(acc+bias) -> bf16 C ; MODE 2: acc+bias+res -> fp32 C
template <int MODE>
__global__ __launch_bounds__(256) void gemm_bf(const unsigned short* __restrict__ A,
                                               const unsigned short* __restrict__ Bw,
                                               const float* __restrict__ bias,
                                               void* __restrict__ Cout,
                                               const float* __restrict__ res,
                                               int M, int N, int K) {
    __shared__ __align__(16) unsigned short As[2][128 * 32];
    __shared__ __align__(16) unsigned short Bs[2][128 * 32];
    const int t = threadIdx.x, l = t & 63, w = t >> 6;
    const int bm = blockIdx.x * 128, bn = blockIdx.y * 128;
    const int wr = w >> 1, wc = w & 1;
    f32x4 acc[4][4] = {};

    const int ra0 = t >> 2, ka0 = (t & 3) * 8;
    const int ra1 = (t + 256) >> 2, ka1 = ((t + 256) & 3) * 8;
    const unsigned short* Ar0 = A + (size_t)min(bm + ra0, M - 1) * K + ka0;
    const unsigned short* Ar1 = A + (size_t)min(bm + ra1, M - 1) * K + ka1;
    const unsigned short* Br0 = Bw + (size_t)(bn + ra0) * K + ka0;
    const unsigned short* Br1 = Bw + (size_t)(bn + ra1) * K + ka1;
    const int lo0 = (0 * 256 + w * 64) * 8, lo1 = (1 * 256 + w * 64) * 8;
    const int lr = l & 15, lk = (l >> 4) * 8;

    gload_lds16(Ar0, As[0] + lo0);
    gload_lds16(Ar1, As[0] + lo1);
    gload_lds16(Br0, Bs[0] + lo0);
    gload_lds16(Br1, Bs[0] + lo1);
    __syncthreads();
    int cur = 0;
    for (int k0 = 0; k0 < K; k0 += 32) {
        if (k0 + 32 < K) {
            gload_lds16(Ar0 + k0 + 32, As[cur ^ 1] + lo0);
            gload_lds16(Ar1 + k0 + 32, As[cur ^ 1] + lo1);
            gload_lds16(Br0 + k0 + 32, Bs[cur ^ 1] + lo0);
            gload_lds16(Br1 + k0 + 32, Bs[cur ^ 1] + lo1);
        }
        bf16x8 a[4], bfr[4];
#pragma unroll
        for (int m = 0; m < 4; m++)
            a[m] = *(const bf16x8*)(As[cur] + (wr * 64 + m * 16 + lr) * 32 + lk);
#pragma unroll
        for (int n = 0; n < 4; n++)
            bfr[n] = *(const bf16x8*)(Bs[cur] + (wc * 64 + n * 16 + lr) * 32 + lk);
#pragma unroll
        for (int m = 0; m < 4; m++)
#pragma unroll
            for (int n = 0; n < 4; n++)
                acc[m][n] = mfma16(a[m], bfr[n], acc[m][n]);
        __syncthreads();
        cur ^= 1;
    }

#pragma unroll
    for (int m = 0; m < 4; m++) {
#pragma unroll
        for (int r = 0; r < 4; r++) {
            int gm = bm + wr * 64 + m * 16 + (l >> 4) * 4 + r;
            if (gm >= M) continue;
#pragma unroll
            for (int n = 0; n < 4; n++) {
                int gn = bn + wc * 64 + n * 16 + lr;
                float vb = acc[m][n][r] + bias[gn];
                if (MODE == 1) {
                    float gl = 0.5f * vb * (1.0f + erff(vb * 0.70710678118f));
                    ((unsigned short*)Cout)[(size_t)gm * N + gn] = f2bf(gl);
                } else {
                    ((float*)Cout)[(size_t)gm * N + gn] = vb + res[(size_t)gm * N + gn];
                }
            }
        }
    }
}

// ---------------- split-K NT GEMM: partials[z][m][n] = A[:,zK..] @ Bw[:,zK..]^T ----------------
// A: M x KFULL (use chunk of 768), Bw: N x KFULL. Grid (M/128, N/128, 4).
__global__ __launch_bounds__(256) void gemm_splitk(const unsigned short* __restrict__ A,
                                                   const unsigned short* __restrict__ Bw,
                                                   float* __restrict__ parts,
                                                   int M, int N, int KFULL) {
    __shared__ __align__(16) unsigned short As[2][128 * 32];
    __shared__ __align__(16) unsigned short Bs[2][128 * 32];
    const int t = threadIdx.x, l = t & 63, w = t >> 6;
    const int bm = blockIdx.x * 128, bn = blockIdx.y * 128;
    const int kbeg = blockIdx.z * 768;
    const int wr = w >> 1, wc = w & 1;
    f32x4 acc[4][4] = {};

    const int ra0 = t >> 2, ka0 = (t & 3) * 8;
    const int ra1 = (t + 256) >> 2, ka1 = ((t + 256) & 3) * 8;
    const unsigned short* Ar0 = A + (size_t)min(bm + ra0, M - 1) * KFULL + kbeg + ka0;
    const unsigned short* Ar1 = A + (size_t)min(bm + ra1, M - 1) * KFULL + kbeg + ka1;
    const unsigned short* Br0 = Bw + (size_t)(bn + ra0) * KFULL + kbeg + ka0;
    const unsigned short* Br1 = Bw + (size_t)(bn + ra1) * KFULL + kbeg + ka1;
    const int lo0 = (0 * 256 + w * 64) * 8, lo1 = (1 * 256 + w * 64) * 8;
    const int lr = l & 15, lk = (l >> 4) * 8;

    gload_lds16(Ar0, As[0] + lo0);
    gload_lds16(Ar1, As[0] + lo1);
    gload_lds16(Br0, Bs[0] + lo0);
    gload_lds16(Br1, Bs[0] + lo1);
    __syncthreads();
    int cur = 0;
    for (int k0 = 0; k0 < 768; k0 += 32) {
        if (k0 + 32 < 768) {
            gload_lds16(Ar0 + k0 + 32, As[cur ^ 1] + lo0);
            gload_lds16(Ar1 + k0 + 32, As[cur ^ 1] + lo1);
            gload_lds16(Br0 + k0 + 32, Bs[cur ^ 1] + lo0);
            gload_lds16(Br1 + k0 + 32, Bs[cur ^ 1] + lo1);
        }
        bf16x8 a[4], bfr[4];
#pragma unroll
        for (int m = 0; m < 4; m++)
            a[m] = *(const bf16x8*)(As[cur] + (wr * 64 + m * 16 + lr) * 32 + lk);
#pragma unroll
        for (int n = 0; n < 4; n++)
            bfr[n] = *(const bf16x8*)(Bs[cur] + (wc * 64 + n * 16 + lr) * 32 + lk);
#pragma unroll
        for (int m = 0; m < 4; m++)
#pragma unroll
            for (int n = 0; n < 4; n++)
                acc[m][n] = mfma16(a[m], bfr[n], acc[m][n]);
        __syncthreads();
        cur ^= 1;
    }

    float* po = parts + (size_t)blockIdx.z * M * N;
#pragma unroll
    for (int m = 0; m < 4; m++) {
#pragma unroll
        for (int r = 0; r < 4; r++) {
            int gm = bm + wr * 64 + m * 16 + (l >> 4) * 4 + r;
            if (gm >= M) continue;
#pragma unroll
            for (int n = 0; n < 4; n++) {
                int gn = bn + wc * 64 + n * 16 + lr;
                po[(size_t)gm * N + gn] = acc[m][n][r];
            }
        }
    }
}

// ---------------- classifier head ----------------
__global__ __launch_bounds__(256) void head_kernel(const float* __restrict__ x,
                                                   const float* __restrict__ Wh,
                                                   const float* __restrict__ bh,
                                                   float* __restrict__ logits) {
    __shared__ float xs[768];
    int b = blockIdx.x;
    int tid = threadIdx.x;
#pragma unroll
    for (int i = 0; i < 3; i++) xs[tid + i * 256] = x[(size_t)b * SEQ * DIM + tid + i * 256];
    __syncthreads();
    int wave = tid >> 6, lane = tid & 63;
    int o = blockIdx.y * 4 + wave;
    if (o < NOUT) {
        float acc = 0;
#pragma unroll
        for (int t = 0; t < 12; t++) {
            int d = lane + t * 64;
            acc = fmaf(xs[d], Wh[(size_t)o * DIM + d], acc);
        }
#pragma unroll
        for (int off = 32; off > 0; off >>= 1) acc += __shfl_down(acc, off, 64);
        if (lane == 0) logits[b * NOUT + o] = acc + bh[o];
    }
}

__global__ __launch_bounds__(256) void softmax_kernel(const float* __restrict__ logits,
                                                      float* __restrict__ out) {
    __shared__ float tmp[4];
    int b = blockIdx.x, tid = threadIdx.x;
    float vals[4];
    float mx = -1e30f;
#pragma unroll
    for (int i = 0; i < 4; i++) {
        int c = tid + i * 256;
        vals[i] = (c < NOUT) ? logits[b * NOUT + c] : -1e30f;
        mx = fmaxf(mx, vals[i]);
    }
#pragma unroll
    for (int o = 32; o > 0; o >>= 1) mx = fmaxf(mx, __shfl_down(mx, o, 64));
    int wave = tid >> 6, lane = tid & 63;
    __syncthreads();
    if (lane == 0) tmp[wave] = mx;
    __syncthreads();
    mx = fmaxf(fmaxf(tmp[0], tmp[1]), fmaxf(tmp[2], tmp[3]));
    float s = 0;
#pragma unroll
    for (int i = 0; i < 4; i++) {
        int c = tid + i * 256;
        if (c < NOUT) {
            vals[i] = __expf(vals[i] - mx);
            s += vals[i];
        } else vals[i] = 0.f;
    }
#pragma unroll
    for (int o = 32; o > 0; o >>= 1) s += __shfl_down(s, o, 64);
    __syncthreads();
    if (lane == 0) tmp[wave] = s;
    __syncthreads();
    s = tmp[0] + tmp[1] + tmp[2] + tmp[3];
    float invs = 1.0f / s;
#pragma unroll
    for (int i = 0; i < 4; i++) {
        int c = tid + i * 256;
        if (c < NOUT) out[b * NOUT + c] = vals[i] * invs;
    }
}

extern "C" void kernel_launch(void* const* d_in, const int* in_sizes, int n_in,
                              void* d_out, int out_size, void* d_ws, size_t ws_size,
                              hipStream_t stream) {
    const float* images = (const float*)d_in[0];
    const float* Wp   = (const float*)d_in[1];
    const float* bp   = (const float*)d_in[2];
    const float* cls  = (const float*)d_in[3];
    const float* pos  = (const float*)d_in[4];
    const float* ln1g = (const float*)d_in[5];
    const float* ln1b = (const float*)d_in[6];
    const float* Wq   = (const float*)d_in[7];
    const float* bq   = (const float*)d_in[8];
    const float* Wk   = (const float*)d_in[9];
    const float* bk   = (const float*)d_in[10];
    const float* Wv   = (const float*)d_in[11];
    const float* bv   = (const float*)d_in[12];
    const float* ln2g = (const float*)d_in[13];
    const float* ln2b = (const float*)d_in[14];
    const float* W1   = (const float*)d_in[15];
    const float* b1   = (const float*)d_in[16];
    const float* W2   = (const float*)d_in[17];
    const float* b2   = (const float*)d_in[18];
    const float* Wh   = (const float*)d_in[19];
    const float* bh   = (const float*)d_in[20];
    float* out = (float*)d_out;

    const size_t NX = (size_t)MROWS * DIM;              // 4,841,472
    const size_t NIMG = (size_t)NBATCH * 3 * 224 * 224; // 4,816,896
    const size_t NW = (size_t)MDIM * DIM;               // 2,359,296 per layer

    char* p = (char*)d_ws;
    float* x      = (float*)p;            p += NX * 4;
    float* h      = (float*)p;            p += NX * 4;
    float* logits = (float*)p;            p += (size_t)NBATCH * NOUT * 4;
    unsigned short* hbf   = (unsigned short*)p; p += NX * 2;
    unsigned short* h2bf  = (unsigned short*)p; p += NX * 2;
    unsigned short* qb    = (unsigned short*)p; p += NX * 2;
    unsigned short* kb    = (unsigned short*)p; p += NX * 2;
    unsigned short* vb    = (unsigned short*)p; p += NX * 2;
    unsigned short* mid   = (unsigned short*)p; p += (size_t)MROWS * MDIM * 2;
    unsigned short* wqkvb = (unsigned short*)p; p += (size_t)NLAYER * NHEAD * 12288 * 2;
    unsigned short* imgbf = (unsigned short*)p; p += NIMG * 2;
    unsigned short* wpbf  = (unsigned short*)p; p += (size_t)DIM * DIM * 2;

    size_t used = (size_t)(p - (char*)d_ws);
    // split-K partials: 4 * MROWS * DIM fp32 = 77.5 MB
    bool skq = ws_size >= used + (size_t)4 * NX * 4;
    float* parts = (float*)p;
    if (skq) p += (size_t)4 * NX * 4;
    used = (size_t)(p - (char*)d_ws);
    // big path: all-layer W1/W2 pre-conversion (113.2 MB)
    bool big = ws_size >= used + (size_t)2 * NLAYER * NW * 2;
    unsigned short* w1a = (unsigned short*)p;
    unsigned short* w2a = big ? w1a + (size_t)NLAYER * NW : w1a + NW;

    cls_pos_kernel<<<dim3(NBATCH), dim3(256), 0, stream>>>(cls, pos, x);
    cvt4<<<dim3(2048), dim3(256), 0, stream>>>(images, imgbf, (int)(NIMG / 4));
    cvt4<<<dim3(576), dim3(256), 0, stream>>>(Wp, wpbf, (int)(DIM * DIM / 4));
    cvt_qkvw<<<dim3(1024), dim3(256), 0, stream>>>(Wq, Wk, Wv, wqkvb);
    gemm_patch_bf<<<dim3(49, 6), dim3(256), 0, stream>>>(imgbf, wpbf, bp, pos, x);
    if (big) {
        cvt4<<<dim3(2048), dim3(256), 0, stream>>>(W1, w1a, (int)(NLAYER * NW / 4));
        cvt4<<<dim3(2048), dim3(256), 0, stream>>>(W2, w2a, (int)(NLAYER * NW / 4));
    }

    for (int l = 0; l < NLAYER; l++) {
        const unsigned short* wl1 = big ? w1a + (size_t)l * NW : w1a;
        const unsigned short* wl2 = big ? w2a + (size_t)l * NW : w2a;
        if (!big) {
            cvt4<<<dim3(2048), dim3(256), 0, stream>>>(W1 + (size_t)l * NW, w1a, (int)(NW / 4));
            cvt4<<<dim3(2048), dim3(256), 0, stream>>>(W2 + (size_t)l * NW, w1a + NW, (int)(NW / 4));
        }
        if (skq && l > 0) {
            // fused: x += b2[l-1] + sum(partials); hbf = LN(x)
            ln_wave<0, 1><<<dim3(MROWS / 4), dim3(256), 0, stream>>>(
                x, nullptr, x, hbf, ln1g + l * DIM, ln1b + l * DIM, parts, b2 + (l - 1) * DIM);
        } else {
            ln_wave<0, 0><<<dim3(MROWS / 4), dim3(256), 0, stream>>>(
                x, nullptr, nullptr, hbf, ln1g + l * DIM, ln1b + l * DIM, nullptr, nullptr);
        }
        qkv_mfma<<<dim3(50, 12), dim3(256), 0, stream>>>(
            hbf, wqkvb + (size_t)l * NHEAD * 12288,
            bq + l * NHEAD * DH, bk + l * NHEAD * DH, bv + l * NHEAD * DH,
            qb, kb, vb);
        attn_mfma<<<dim3(NBATCH, NHEAD), dim3(256), 0, stream>>>(qb, kb, vb, h);
        ln_wave<1, 0><<<dim3(MROWS / 4), dim3(256), 0, stream>>>(
            x, h, x, h2bf, ln2g + l * DIM, ln2b + l * DIM, nullptr, nullptr);
        gemm_bf<1><<<dim3(50, 24), dim3(256), 0, stream>>>(
            h2bf, wl1, b1 + l * MDIM, mid, nullptr, MROWS, MDIM, DIM);
        if (skq) {
            gemm_splitk<<<dim3(50, 6, 4), dim3(256), 0, stream>>>(
                mid, wl2, parts, MROWS, DIM, MDIM);
        } else {
            gemm_bf<2><<<dim3(50, 6), dim3(256), 0, stream>>>(
                mid, wl2, b2 + l * DIM, x, x, MROWS, DIM, MDIM);
        }
    }
    if (skq) {
        reduce4<<<dim3(MROWS / 4), dim3(256), 0, stream>>>(x, parts, b2 + (NLAYER - 1) * DIM);
    }

    head_kernel<<<dim3(NBATCH, 250), dim3(256), 0, stream>>>(x, Wh, bh, logits);
    softmax_kernel<<<dim3(NBATCH), dim3(256), 0, stream>>>(logits, out);
}

// Round 5
// 2745.839 us; speedup vs baseline: 7.9171x; 1.0335x over previous
//
#include <hip/hip_runtime.h>
#include <math.h>
#include <stdint.h>

#define NBATCH 32
#define SEQ 197
#define DIM 768
#define NHEAD 12
#define DH 64
#define MDIM 3072
#define NLAYER 12
#define NPATCH 196
#define NOUT 1000
#define MROWS (NBATCH * SEQ)   // 6304
#define SPLITK 2

typedef __bf16 bf16x8 __attribute__((ext_vector_type(8)));
typedef float f32x4 __attribute__((ext_vector_type(4)));

__device__ __forceinline__ unsigned short f2bf(float f) {
    unsigned u = __float_as_uint(f);
    unsigned r = u + 0x7fffu + ((u >> 16) & 1u);
    return (unsigned short)(r >> 16);
}

__device__ __forceinline__ f32x4 mfma16(bf16x8 a, bf16x8 b, f32x4 c) {
    return __builtin_amdgcn_mfma_f32_16x16x32_bf16(a, b, c, 0, 0, 0);
}

// async global->LDS 16B: lds pointer wave-uniform base; HW writes lane l at base + l*16.
__device__ __forceinline__ void gload_lds16(const void* g, const void* lds) {
    __builtin_amdgcn_global_load_lds(
        (const __attribute__((address_space(1))) void*)(uintptr_t)g,
        (__attribute__((address_space(3))) void*)(uint32_t)(uintptr_t)lds,
        16, 0, 0);
}

// counted-vmcnt barrier pair: wait own oldest loads only; prefetch stays in flight.
#define WAIT_VMCNT_4() asm volatile("s_waitcnt vmcnt(4)" ::: "memory")
#define WAIT_VMCNT_0() asm volatile("s_waitcnt vmcnt(0)" ::: "memory")
#define BARRIER_RAW()                      \
    do {                                   \
        asm volatile("" ::: "memory");     \
        __builtin_amdgcn_s_barrier();      \
        asm volatile("" ::: "memory");     \
    } while (0)

// ---------------- fp32 -> bf16 converter (grid-stride) ----------------
__global__ __launch_bounds__(256) void cvt4(const float* __restrict__ src,
                                            unsigned short* __restrict__ dst, int n4) {
    int stride = gridDim.x * 256;
    for (int i = blockIdx.x * 256 + threadIdx.x; i < n4; i += stride) {
        float4 f = *(const float4*)(src + (size_t)i * 4);
        ushort4 o;
        o.x = f2bf(f.x); o.y = f2bf(f.y); o.z = f2bf(f.z); o.w = f2bf(f.w);
        *(ushort4*)(dst + (size_t)i * 4) = o;
    }
}

// gather Wq/Wk/Wv [L][H][e][d] -> wqkvb [L][H][3*64 rows][64] bf16
__global__ __launch_bounds__(256) void cvt_qkvw(const float* __restrict__ Wq,
                                                const float* __restrict__ Wk,
                                                const float* __restrict__ Wv,
                                                unsigned short* __restrict__ dst) {
    const int n = NLAYER * NHEAD * 3 * 64 * 64;
    int stride = gridDim.x * 256;
    for (int i = blockIdx.x * 256 + threadIdx.x; i < n; i += stride) {
        int d = i & 63, e = (i >> 6) & 63;
        int v = i >> 12;
        int t = v % 3, hh = (v / 3) % NHEAD, l = v / (3 * NHEAD);
        const float* src = (t == 0) ? Wq : (t == 1) ? Wk : Wv;
        dst[i] = f2bf(src[(((size_t)(l * NHEAD + hh)) * 64 + e) * 64 + d]);
    }
}

// ---------------- cls + pos init ----------------
__global__ __launch_bounds__(256) void cls_pos_kernel(const float* __restrict__ cls,
                                                      const float* __restrict__ pos,
                                                      float* __restrict__ x) {
    int b = blockIdx.x, tid = threadIdx.x;
#pragma unroll
    for (int i = 0; i < 3; i++) {
        int c = tid + i * 256;
        x[(size_t)b * SEQ * DIM + c] = cls[c] + pos[c];
    }
}

// ---------------- patch-embed GEMM: bf16 MFMA, gathered A, counted-vmcnt dbuf ----------------
__global__ __launch_bounds__(256) void gemm_patch_bf(const unsigned short* __restrict__ imgbf,
                                                     const unsigned short* __restrict__ wpbf,
                                                     const float* __restrict__ bp,
                                                     const float* __restrict__ pos,
                                                     float* __restrict__ x) {
    __shared__ __align__(16) unsigned short As[2][128 * 32];
    __shared__ __align__(16) unsigned short Bs[2][128 * 32];
    const int t = threadIdx.x, l = t & 63, w = t >> 6;
    const int bm = blockIdx.x * 128, bn = blockIdx.y * 128;
    const int wr = w >> 1, wc = w & 1;
    f32x4 acc[4][4] = {};

    const int ra0 = t >> 2, ka0 = (t & 3) * 8;
    const int ra1 = (t + 256) >> 2, ka1 = ((t + 256) & 3) * 8;
    int gm0 = bm + ra0, b0 = gm0 / NPATCH, p0 = gm0 % NPATCH;
    int gm1 = bm + ra1, b1 = gm1 / NPATCH, p1 = gm1 % NPATCH;
    const unsigned short* ib0 =
        imgbf + ((size_t)b0 * 3 * 224 + (size_t)(p0 / 14) * 16) * 224 + (p0 % 14) * 16;
    const unsigned short* ib1 =
        imgbf + ((size_t)b1 * 3 * 224 + (size_t)(p1 / 14) * 16) * 224 + (p1 % 14) * 16;
    const unsigned short* Br0 = wpbf + (size_t)(bn + ra0) * 768 + ka0;
    const unsigned short* Br1 = wpbf + (size_t)(bn + ra1) * 768 + ka1;
    const int lA0 = (0 * 256 + w * 64) * 8, lA1 = (1 * 256 + w * 64) * 8;
    const int lr = l & 15, lk = (l >> 4) * 8;

#define PATCH_STAGE(buf, k0)                                                   \
    {                                                                          \
        int kA0 = (k0) + ka0, kA1 = (k0) + ka1;                                \
        int c0 = kA0 >> 8, i0 = (kA0 >> 4) & 15, j0 = kA0 & 15;                \
        int c1 = kA1 >> 8, i1 = (kA1 >> 4) & 15, j1 = kA1 & 15;                \
        gload_lds16(ib0 + ((size_t)c0 * 224 + i0) * 224 + j0, As[buf] + lA0);  \
        gload_lds16(ib1 + ((size_t)c1 * 224 + i1) * 224 + j1, As[buf] + lA1);  \
        gload_lds16(Br0 + (k0), Bs[buf] + lA0);                                \
        gload_lds16(Br1 + (k0), Bs[buf] + lA1);                                \
    }

    PATCH_STAGE(0, 0);
    int cur = 0;
    for (int k0 = 0; k0 < 768; k0 += 32) {
        if (k0 + 32 < 768) {
            PATCH_STAGE(cur ^ 1, k0 + 32);
            WAIT_VMCNT_4();
        } else {
            WAIT_VMCNT_0();
        }
        BARRIER_RAW();
        bf16x8 a[4], bfr[4];
#pragma unroll
        for (int m = 0; m < 4; m++)
            a[m] = *(const bf16x8*)(As[cur] + (wr * 64 + m * 16 + lr) * 32 + lk);
#pragma unroll
        for (int n = 0; n < 4; n++)
            bfr[n] = *(const bf16x8*)(Bs[cur] + (wc * 64 + n * 16 + lr) * 32 + lk);
#pragma unroll
        for (int m = 0; m < 4; m++)
#pragma unroll
            for (int n = 0; n < 4; n++)
                acc[m][n] = mfma16(a[m], bfr[n], acc[m][n]);
        BARRIER_RAW();
        cur ^= 1;
    }
#undef PATCH_STAGE

#pragma unroll
    for (int m = 0; m < 4; m++) {
#pragma unroll
        for (int r = 0; r < 4; r++) {
            int gm = bm + wr * 64 + m * 16 + (l >> 4) * 4 + r;
            int b2 = gm / NPATCH, p2 = gm % NPATCH;
            size_t orow = (size_t)(b2 * SEQ + 1 + p2) * DIM;
#pragma unroll
            for (int n = 0; n < 4; n++) {
                int gn = bn + wc * 64 + n * 16 + lr;
                x[orow + gn] = acc[m][n][r] + bp[gn] + pos[(size_t)(1 + p2) * DIM + gn];
            }
        }
    }
}

// ---------------- wave-per-row LayerNorm, bf16 h out ----------------
// RES: v = x + addv, write x_out.  RED: v = x + badd + sum(SPLITK partials), write x_out.
template <int RES, int RED>
__global__ __launch_bounds__(256) void ln_wave(const float* __restrict__ x_in,
                                               const float* __restrict__ addv,
                                               float* __restrict__ x_out,
                                               unsigned short* __restrict__ h_out,
                                               const float* __restrict__ g,
                                               const float* __restrict__ bb,
                                               const float* __restrict__ parts,
                                               const float* __restrict__ badd) {
    int w = threadIdx.x >> 6, l = threadIdx.x & 63;
    size_t row = (size_t)blockIdx.x * 4 + w;
    const float* xr = x_in + row * DIM;
    float4 v[3];
    float s = 0.f;
#pragma unroll
    for (int u = 0; u < 3; u++) {
        int c = u * 256 + l * 4;
        v[u] = *(const float4*)(xr + c);
        if (RES) {
            float4 a4 = *(const float4*)(addv + row * DIM + c);
            v[u].x += a4.x; v[u].y += a4.y; v[u].z += a4.z; v[u].w += a4.w;
        }
        if (RED) {
            float4 b4 = *(const float4*)(badd + c);
            v[u].x += b4.x; v[u].y += b4.y; v[u].z += b4.z; v[u].w += b4.w;
#pragma unroll
            for (int kc = 0; kc < SPLITK; kc++) {
                float4 p4 = *(const float4*)(parts + ((size_t)kc * MROWS + row) * DIM + c);
                v[u].x += p4.x; v[u].y += p4.y; v[u].z += p4.z; v[u].w += p4.w;
            }
        }
        s += v[u].x + v[u].y + v[u].z + v[u].w;
    }
#pragma unroll
    for (int o = 1; o < 64; o <<= 1) s += __shfl_xor(s, o, 64);
    float mean = s * (1.0f / 768.0f);
    float s2 = 0.f;
#pragma unroll
    for (int u = 0; u < 3; u++) {
        float dx = v[u].x - mean, dy = v[u].y - mean, dz = v[u].z - mean, dw = v[u].w - mean;
        s2 += dx * dx + dy * dy + dz * dz + dw * dw;
    }
#pragma unroll
    for (int o = 1; o < 64; o <<= 1) s2 += __shfl_xor(s2, o, 64);
    float inv = rsqrtf(s2 * (1.0f / 768.0f) + 1e-5f);
#pragma unroll
    for (int u = 0; u < 3; u++) {
        int c = u * 256 + l * 4;
        float4 g4 = *(const float4*)(g + c);
        float4 b4 = *(const float4*)(bb + c);
        ushort4 o;
        o.x = f2bf((v[u].x - mean) * inv * g4.x + b4.x);
        o.y = f2bf((v[u].y - mean) * inv * g4.y + b4.y);
        o.z = f2bf((v[u].z - mean) * inv * g4.z + b4.z);
        o.w = f2bf((v[u].w - mean) * inv * g4.w + b4.w);
        *(ushort4*)(h_out + row * DIM + c) = o;
        if (RES || RED) *(float4*)(x_out + row * DIM + c) = v[u];
    }
}

// ---------------- final split-K reduce: x += badd + sum(SPLITK partials) ----------------
__global__ __launch_bounds__(256) void reduceK(float* __restrict__ x,
                                               const float* __restrict__ parts,
                                               const float* __restrict__ badd) {
    int w = threadIdx.x >> 6, l = threadIdx.x & 63;
    size_t row = (size_t)blockIdx.x * 4 + w;
#pragma unroll
    for (int u = 0; u < 3; u++) {
        int c = u * 256 + l * 4;
        float4 v = *(const float4*)(x + row * DIM + c);
        float4 b4 = *(const float4*)(badd + c);
        v.x += b4.x; v.y += b4.y; v.z += b4.z; v.w += b4.w;
#pragma unroll
        for (int kc = 0; kc < SPLITK; kc++) {
            float4 p4 = *(const float4*)(parts + ((size_t)kc * MROWS + row) * DIM + c);
            v.x += p4.x; v.y += p4.y; v.z += p4.z; v.w += p4.w;
        }
        *(float4*)(x + row * DIM + c) = v;
    }
}

// ---------------- QKV projection: per-head MFMA, K=64 ----------------
__global__ __launch_bounds__(256) void qkv_mfma(const unsigned short* __restrict__ hbf,
                                                const unsigned short* __restrict__ wqkv,
                                                const float* __restrict__ bq,
                                                const float* __restrict__ bk,
                                                const float* __restrict__ bv,
                                                unsigned short* __restrict__ q,
                                                unsigned short* __restrict__ k,
                                                unsigned short* __restrict__ v) {
    __shared__ __align__(16) unsigned short As[2 * 128 * 32];
    __shared__ __align__(16) unsigned short Bs[2 * 192 * 32];
    const int bm = blockIdx.x * 128, hd = blockIdx.y;
    const int t = threadIdx.x, l = t & 63, w = t >> 6;
    const unsigned short* wh = wqkv + (size_t)hd * 12288;

#pragma unroll
    for (int i = 0; i < 4; i++) {
        int p = t + i * 256;
        int kt = p >> 9, r = (p >> 2) & 127, kc = p & 3;
        int grow = min(bm + r, MROWS - 1);
        gload_lds16(hbf + (size_t)grow * DIM + hd * 64 + kt * 32 + kc * 8,
                    As + (size_t)(i * 256 + w * 64) * 8);
    }
#pragma unroll
    for (int i = 0; i < 6; i++) {
        int p = t + i * 256;
        int kt = p / 768, rem = p - kt * 768;
        int r = rem >> 2, kc = rem & 3;
        gload_lds16(wh + (size_t)r * 64 + kt * 32 + kc * 8,
                    Bs + (size_t)(i * 256 + w * 64) * 8);
    }
    __syncthreads();

    f32x4 acc[4][6] = {};
    const int wr = w >> 1, wc = w & 1;
    const int lr = l & 15, lk = (l >> 4) * 8;
#pragma unroll
    for (int ks = 0; ks < 2; ks++) {
        bf16x8 a[4], bfr[6];
#pragma unroll
        for (int m = 0; m < 4; m++)
            a[m] = *(const bf16x8*)(As + ks * 4096 + (wr * 64 + m * 16 + lr) * 32 + lk);
#pragma unroll
        for (int n = 0; n < 6; n++)
            bfr[n] = *(const bf16x8*)(Bs + ks * 6144 + (wc * 96 + n * 16 + lr) * 32 + lk);
#pragma unroll
        for (int m = 0; m < 4; m++)
#pragma unroll
            for (int n = 0; n < 6; n++)
                acc[m][n] = mfma16(a[m], bfr[n], acc[m][n]);
    }
#pragma unroll
    for (int n = 0; n < 6; n++) {
        int c = wc * 96 + n * 16 + lr;
        int tt = c >> 6, e = c & 63;
        const float* bias = (tt == 0) ? bq : (tt == 1) ? bk : bv;
        unsigned short* outp = (tt == 0) ? q : (tt == 1) ? k : v;
        float bval = bias[hd * 64 + e];
#pragma unroll
        for (int m = 0; m < 4; m++) {
#pragma unroll
            for (int r = 0; r < 4; r++) {
                int gm = bm + wr * 64 + m * 16 + (l >> 4) * 4 + r;
                if (gm < MROWS) outp[(size_t)gm * DIM + hd * 64 + e] = f2bf(acc[m][n][r] + bval);
            }
        }
    }
}

// ---------------- fused attention: MFMA, swapped QK^T, per-wave P in LDS ----------------
__global__ __launch_bounds__(256) void attn_mfma(const unsigned short* __restrict__ qg,
                                                 const unsigned short* __restrict__ kg,
                                                 const unsigned short* __restrict__ vg,
                                                 float* __restrict__ o) {
    __shared__ __align__(16) unsigned short Vt[64][232];   // V transposed [d][j], pad to 232
    __shared__ __align__(16) unsigned short P[4][16][232]; // per-wave P [q][j]
    const int b = blockIdx.x, hd = blockIdx.y;
    const int t = threadIdx.x, l = t & 63, w = t >> 6;
    const size_t base = ((size_t)b * SEQ) * DIM + hd * DH;

    for (int idx = t; idx < 224 * 16; idx += 256) {
        int j = idx >> 4, dg = idx & 15;
        if (j < SEQ) {
            ushort4 v4 = *(const ushort4*)(vg + base + (size_t)j * DIM + dg * 4);
            Vt[dg * 4 + 0][j] = v4.x; Vt[dg * 4 + 1][j] = v4.y;
            Vt[dg * 4 + 2][j] = v4.z; Vt[dg * 4 + 3][j] = v4.w;
        } else {
            Vt[dg * 4 + 0][j] = 0; Vt[dg * 4 + 1][j] = 0;
            Vt[dg * 4 + 2][j] = 0; Vt[dg * 4 + 3][j] = 0;
        }
    }
    {
        int qq = l & 15, jj = 208 + (l >> 4) * 4;
        P[w][qq][jj] = 0; P[w][qq][jj + 1] = 0; P[w][qq][jj + 2] = 0; P[w][qq][jj + 3] = 0;
    }
    __syncthreads();

    const int lr = l & 15, lk4 = (l >> 4);
    for (int qt = w; qt < 13; qt += 4) {
        int qrow = min(qt * 16 + lr, SEQ - 1);
        const unsigned short* qp = qg + base + (size_t)qrow * DIM + lk4 * 8;
        bf16x8 q0 = *(const bf16x8*)qp;
        bf16x8 q1 = *(const bf16x8*)(qp + 32);
        f32x4 st[13];
#pragma unroll
        for (int jt = 0; jt < 13; jt++) st[jt] = (f32x4){0.f, 0.f, 0.f, 0.f};
#pragma unroll
        for (int jt = 0; jt < 13; jt++) {
            int jrow = min(jt * 16 + lr, SEQ - 1);
            const unsigned short* kp = kg + base + (size_t)jrow * DIM + lk4 * 8;
            bf16x8 k0 = *(const bf16x8*)kp;
            bf16x8 k1 = *(const bf16x8*)(kp + 32);
            st[jt] = mfma16(k0, q0, st[jt]);   // S^T[j][q]
            st[jt] = mfma16(k1, q1, st[jt]);
        }
        float mx = -1e30f;
#pragma unroll
        for (int jt = 0; jt < 13; jt++)
#pragma unroll
            for (int r = 0; r < 4; r++) {
                int j = jt * 16 + lk4 * 4 + r;
                float sv = st[jt][r] * 0.125f;
                st[jt][r] = (j < SEQ) ? sv : -1e30f;
                mx = fmaxf(mx, st[jt][r]);
            }
        mx = fmaxf(mx, __shfl_xor(mx, 16, 64));
        mx = fmaxf(mx, __shfl_xor(mx, 32, 64));
        float sum = 0.f;
#pragma unroll
        for (int jt = 0; jt < 13; jt++)
#pragma unroll
            for (int r = 0; r < 4; r++) {
                float p = __expf(st[jt][r] - mx);
                st[jt][r] = p;
                sum += p;
            }
        sum += __shfl_xor(sum, 16, 64);
        sum += __shfl_xor(sum, 32, 64);
        float inv = 1.0f / sum;
#pragma unroll
        for (int jt = 0; jt < 13; jt++) {
            ushort4 pk;
            pk.x = f2bf(st[jt][0] * inv); pk.y = f2bf(st[jt][1] * inv);
            pk.z = f2bf(st[jt][2] * inv); pk.w = f2bf(st[jt][3] * inv);
            *(ushort4*)&P[w][lr][jt * 16 + lk4 * 4] = pk;
        }
        f32x4 acc[4] = {};
#pragma unroll
        for (int kt = 0; kt < 7; kt++) {
            bf16x8 pa = *(const bf16x8*)&P[w][lr][kt * 32 + lk4 * 8];
#pragma unroll
            for (int nt = 0; nt < 4; nt++) {
                bf16x8 bv = *(const bf16x8*)&Vt[nt * 16 + lr][kt * 32 + lk4 * 8];
                acc[nt] = mfma16(pa, bv, acc[nt]);
            }
        }
#pragma unroll
        for (int nt = 0; nt < 4; nt++)
#pragma unroll
            for (int r = 0; r < 4; r++) {
                int qq = qt * 16 + lk4 * 4 + r;
                if (qq < SEQ) o[base + (size_t)qq * DIM + nt * 16 + lr] = acc[nt][r];
            }
    }
}

// ---------------- bf16 MFMA NT GEMM, 128x128 tile, counted-vmcnt dbuf ----------------
// MODE 1: gelu(acc+bias) -> bf16 C ; MODE 2: acc+bias+res -> fp32 C
template <int MODE>
__global__ __launch_bounds__(256) void gemm_bf(const unsigned short* __restrict__ A,
                                               const unsigned short* __restrict__ Bw,
                                               const float* __restrict__ bias,
                                               void* __restrict__ Cout,
                                               const float* __restrict__ res,
                                               int M, int N, int K) {
    __shared__ __align__(16) unsigned short As[2][128 * 32];
    __shared__ __align__(16) unsigned short Bs[2][128 * 32];
    const int t = threadIdx.x, l = t & 63, w = t >> 6;
    const int bm = blockIdx.x * 128, bn = blockIdx.y * 128;
    const int wr = w >> 1, wc = w & 1;
    f32x4 acc[4][4] = {};

    const int ra0 = t >> 2, ka0 = (t & 3) * 8;
    const int ra1 = (t + 256) >> 2, ka1 = ((t + 256) & 3) * 8;
    const unsigned short* Ar0 = A + (size_t)min(bm + ra0, M - 1) * K + ka0;
    const unsigned short* Ar1 = A + (size_t)min(bm + ra1, M - 1) * K + ka1;
    const unsigned short* Br0 = Bw + (size_t)(bn + ra0) * K + ka0;
    const unsigned short* Br1 = Bw + (size_t)(bn + ra1) * K + ka1;
    const int lo0 = (0 * 256 + w * 64) * 8, lo1 = (1 * 256 + w * 64) * 8;
    const int lr = l & 15, lk = (l >> 4) * 8;

    gload_lds16(Ar0, As[0] + lo0);
    gload_lds16(Ar1, As[0] + lo1);
    gload_lds16(Br0, Bs[0] + lo0);
    gload_lds16(Br1, Bs[0] + lo1);
    int cur = 0;
    for (int k0 = 0; k0 < K; k0 += 32) {
        if (k0 + 32 < K) {
            gload_lds16(Ar0 + k0 + 32, As[cur ^ 1] + lo0);
            gload_lds16(Ar1 + k0 + 32, As[cur ^ 1] + lo1);
            gload_lds16(Br0 + k0 + 32, Bs[cur ^ 1] + lo0);
            gload_lds16(Br1 + k0 + 32, Bs[cur ^ 1] + lo1);
            WAIT_VMCNT_4();
        } else {
            WAIT_VMCNT_0();
        }
        BARRIER_RAW();
        bf16x8 a[4], bfr[4];
#pragma unroll
        for (int m = 0; m < 4; m++)
            a[m] = *(const bf16x8*)(As[cur] + (wr * 64 + m * 16 + lr) * 32 + lk);
#pragma unroll
        for (int n = 0; n < 4; n++)
            bfr[n] = *(const bf16x8*)(Bs[cur] + (wc * 64 + n * 16 + lr) * 32 + lk);
#pragma unroll
        for (int m = 0; m < 4; m++)
#pragma unroll
            for (int n = 0; n < 4; n++)
                acc[m][n] = mfma16(a[m], bfr[n], acc[m][n]);
        BARRIER_RAW();
        cur ^= 1;
    }

#pragma unroll
    for (int m = 0; m < 4; m++) {
#pragma unroll
        for (int r = 0; r < 4; r++) {
            int gm = bm + wr * 64 + m * 16 + (l >> 4) * 4 + r;
            if (gm >= M) continue;
#pragma unroll
            for (int n = 0; n < 4; n++) {
                int gn = bn + wc * 64 + n * 16 + lr;
                float vb = acc[m][n][r] + bias[gn];
                if (MODE == 1) {
                    float gl = 0.5f * vb * (1.0f + erff(vb * 0.70710678118f));
                    ((unsigned short*)Cout)[(size_t)gm * N + gn] = f2bf(gl);
                } else {
                    ((float*)Cout)[(size_t)gm * N + gn] = vb + res[(size_t)gm * N + gn];
                }
            }
        }
    }
}

// ---------------- split-K NT GEMM: partials[z][m][n], K chunk = KFULL/SPLITK ----------------
__global__ __launch_bounds__(256) void gemm_splitk(const unsigned short* __restrict__ A,
                                                   const unsigned short* __restrict__ Bw,
                                                   float* __restrict__ parts,
                                                   int M, int N, int KFULL) {
    __shared__ __align__(16) unsigned short As[2][128 * 32];
    __shared__ __align__(16) unsigned short Bs[2][128 * 32];
    const int t = threadIdx.x, l = t & 63, w = t >> 6;
    const int bm = blockIdx.x * 128, bn = blockIdx.y * 128;
    const int KC = KFULL / SPLITK;
    const int kbeg = blockIdx.z * KC;
    const int wr = w >> 1, wc = w & 1;
    f32x4 acc[4][4] = {};

    const int ra0 = t >> 2, ka0 = (t & 3) * 8;
    const int ra1 = (t + 256) >> 2, ka1 = ((t + 256) & 3) * 8;
    const unsigned short* Ar0 = A + (size_t)min(bm + ra0, M - 1) * KFULL + kbeg + ka0;
    const unsigned short* Ar1 = A + (size_t)min(bm + ra1, M - 1) * KFULL + kbeg + ka1;
    const unsigned short* Br0 = Bw + (size_t)(bn + ra0) * KFULL + kbeg + ka0;
    const unsigned short* Br1 = Bw + (size_t)(bn + ra1) * KFULL + kbeg + ka1;
    const int lo0 = (0 * 256 + w * 64) * 8, lo1 = (1 * 256 + w * 64) * 8;
    const int lr = l & 15, lk = (l >> 4) * 8;

    gload_lds16(Ar0, As[0] + lo0);
    gload_lds16(Ar1, As[0] + lo1);
    gload_lds16(Br0, Bs[0] + lo0);
    gload_lds16(Br1, Bs[0] + lo1);
    int cur = 0;
    for (int k0 = 0; k0 < KC; k0 += 32) {
        if (k0 + 32 < KC) {
            gload_lds16(Ar0 + k0 + 32, As[cur ^ 1] + lo0);
            gload_lds16(Ar1 + k0 + 32, As[cur ^ 1] + lo1);
            gload_lds16(Br0 + k0 + 32, Bs[cur ^ 1] + lo0);
            gload_lds16(Br1 + k0 + 32, Bs[cur ^ 1] + lo1);
            WAIT_VMCNT_4();
        } else {
            WAIT_VMCNT_0();
        }
        BARRIER_RAW();
        bf16x8 a[4], bfr[4];
#pragma unroll
        for (int m = 0; m < 4; m++)
            a[m] = *(const bf16x8*)(As[cur] + (wr * 64 + m * 16 + lr) * 32 + lk);
#pragma unroll
        for (int n = 0; n < 4; n++)
            bfr[n] = *(const bf16x8*)(Bs[cur] + (wc * 64 + n * 16 + lr) * 32 + lk);
#pragma unroll
        for (int m = 0; m < 4; m++)
#pragma unroll
            for (int n = 0; n < 4; n++)
                acc[m][n] = mfma16(a[m], bfr[n], acc[m][n]);
        BARRIER_RAW();
        cur ^= 1;
    }

    float* po = parts + (size_t)blockIdx.z * M * N;
#pragma unroll
    for (int m = 0; m < 4; m++) {
#pragma unroll
        for (int r = 0; r < 4; r++) {
            int gm = bm + wr * 64 + m * 16 + (l >> 4) * 4 + r;
            if (gm >= M) continue;
#pragma unroll
            for (int n = 0; n < 4; n++) {
                int gn = bn + wc * 64 + n * 16 + lr;
                po[(size_t)gm * N + gn] = acc[m][n][r];
            }
        }
    }
}

// ---------------- classifier head ----------------
__global__ __launch_bounds__(256) void head_kernel(const float* __restrict__ x,
                                                   const float* __restrict__ Wh,
                                                   const float* __restrict__ bh,
                                                   float* __restrict__ logits) {
    __shared__ float xs[768];
    int b = blockIdx.x;
    int tid = threadIdx.x;
#pragma unroll
    for (int i = 0; i < 3; i++) xs[tid + i * 256] = x[(size_t)b * SEQ * DIM + tid + i * 256];
    __syncthreads();
    int wave = tid >> 6, lane = tid & 63;
    int o = blockIdx.y * 4 + wave;
    if (o < NOUT) {
        float acc = 0;
#pragma unroll
        for (int t = 0; t < 12; t++) {
            int d = lane + t * 64;
            acc = fmaf(xs[d], Wh[(size_t)o * DIM + d], acc);
        }
#pragma unroll
        for (int off = 32; off > 0; off >>= 1) acc += __shfl_down(acc, off, 64);
        if (lane == 0) logits[b * NOUT + o] = acc + bh[o];
    }
}

__global__ __launch_bounds__(256) void softmax_kernel(const float* __restrict__ logits,
                                                      float* __restrict__ out) {
    __shared__ float tmp[4];
    int b = blockIdx.x, tid = threadIdx.x;
    float vals[4];
    float mx = -1e30f;
#pragma unroll
    for (int i = 0; i < 4; i++) {
        int c = tid + i * 256;
        vals[i] = (c < NOUT) ? logits[b * NOUT + c] : -1e30f;
        mx = fmaxf(mx, vals[i]);
    }
#pragma unroll
    for (int o = 32; o > 0; o >>= 1) mx = fmaxf(mx, __shfl_down(mx, o, 64));
    int wave = tid >> 6, lane = tid & 63;
    __syncthreads();
    if (lane == 0) tmp[wave] = mx;
    __syncthreads();
    mx = fmaxf(fmaxf(tmp[0], tmp[1]), fmaxf(tmp[2], tmp[3]));
    float s = 0;
#pragma unroll
    for (int i = 0; i < 4; i++) {
        int c = tid + i * 256;
        if (c < NOUT) {
            vals[i] = __expf(vals[i] - mx);
            s += vals[i];
        } else vals[i] = 0.f;
    }
#pragma unroll
    for (int o = 32; o > 0; o >>= 1) s += __shfl_down(s, o, 64);
    __syncthreads();
    if (lane == 0) tmp[wave] = s;
    __syncthreads();
    s = tmp[0] + tmp[1] + tmp[2] + tmp[3];
    float invs = 1.0f / s;
#pragma unroll
    for (int i = 0; i < 4; i++) {
        int c = tid + i * 256;
        if (c < NOUT) out[b * NOUT + c] = vals[i] * invs;
    }
}

extern "C" void kernel_launch(void* const* d_in, const int* in_sizes, int n_in,
                              void* d_out, int out_size, void* d_ws, size_t ws_size,
                              hipStream_t stream) {
    const float* images = (const float*)d_in[0];
    const float* Wp   = (const float*)d_in[1];
    const float* bp   = (const float*)d_in[2];
    const float* cls  = (const float*)d_in[3];
    const float* pos  = (const float*)d_in[4];
    const float* ln1g = (const float*)d_in[5];
    const float* ln1b = (const float*)d_in[6];
    const float* Wq   = (const float*)d_in[7];
    const float* bq   = (const float*)d_in[8];
    const float* Wk   = (const float*)d_in[9];
    const float* bk   = (const float*)d_in[10];
    const float* Wv   = (const float*)d_in[11];
    const float* bv   = (const float*)d_in[12];
    const float* ln2g = (const float*)d_in[13];
    const float* ln2b = (const float*)d_in[14];
    const float* W1   = (const float*)d_in[15];
    const float* b1   = (const float*)d_in[16];
    const float* W2   = (const float*)d_in[17];
    const float* b2   = (const float*)d_in[18];
    const float* Wh   = (const float*)d_in[19];
    const float* bh   = (const float*)d_in[20];
    float* out = (float*)d_out;

    const size_t NX = (size_t)MROWS * DIM;              // 4,841,472
    const size_t NIMG = (size_t)NBATCH * 3 * 224 * 224; // 4,816,896
    const size_t NW = (size_t)MDIM * DIM;               // 2,359,296 per layer

    char* p = (char*)d_ws;
    float* x      = (float*)p;            p += NX * 4;
    float* h      = (float*)p;            p += NX * 4;
    float* logits = (float*)p;            p += (size_t)NBATCH * NOUT * 4;
    unsigned short* hbf   = (unsigned short*)p; p += NX * 2;
    unsigned short* h2bf  = (unsigned short*)p; p += NX * 2;
    unsigned short* qb    = (unsigned short*)p; p += NX * 2;
    unsigned short* kb    = (unsigned short*)p; p += NX * 2;
    unsigned short* vb    = (unsigned short*)p; p += NX * 2;
    unsigned short* mid   = (unsigned short*)p; p += (size_t)MROWS * MDIM * 2;
    unsigned short* wqkvb = (unsigned short*)p; p += (size_t)NLAYER * NHEAD * 12288 * 2;
    unsigned short* imgbf = (unsigned short*)p; p += NIMG * 2;
    unsigned short* wpbf  = (unsigned short*)p; p += (size_t)DIM * DIM * 2;

    size_t used = (size_t)(p - (char*)d_ws);
    // split-K partials: SPLITK * MROWS * DIM fp32
    bool skq = ws_size >= used + (size_t)SPLITK * NX * 4;
    float* parts = (float*)p;
    if (skq) p += (size_t)SPLITK * NX * 4;
    used = (size_t)(p - (char*)d_ws);
    // big path: all-layer W1/W2 pre-conversion (113.2 MB)
    bool big = ws_size >= used + (size_t)2 * NLAYER * NW * 2;
    unsigned short* w1a = (unsigned short*)p;
    unsigned short* w2a = big ? w1a + (size_t)NLAYER * NW : w1a + NW;

    cls_pos_kernel<<<dim3(NBATCH), dim3(256), 0, stream>>>(cls, pos, x);
    cvt4<<<dim3(2048), dim3(256), 0, stream>>>(images, imgbf, (int)(NIMG / 4));
    cvt4<<<dim3(576), dim3(256), 0, stream>>>(Wp, wpbf, (int)(DIM * DIM / 4));
    cvt_qkvw<<<dim3(1024), dim3(256), 0, stream>>>(Wq, Wk, Wv, wqkvb);
    gemm_patch_bf<<<dim3(49, 6), dim3(256), 0, stream>>>(imgbf, wpbf, bp, pos, x);
    if (big) {
        cvt4<<<dim3(2048), dim3(256), 0, stream>>>(W1, w1a, (int)(NLAYER * NW / 4));
        cvt4<<<dim3(2048), dim3(256), 0, stream>>>(W2, w2a, (int)(NLAYER * NW / 4));
    }

    for (int l = 0; l < NLAYER; l++) {
        const unsigned short* wl1 = big ? w1a + (size_t)l * NW : w1a;
        const unsigned short* wl2 = big ? w2a + (size_t)l * NW : w2a;
        if (!big) {
            cvt4<<<dim3(2048), dim3(256), 0, stream>>>(W1 + (size_t)l * NW, w1a, (int)(NW / 4));
            cvt4<<<dim3(2048), dim3(256), 0, stream>>>(W2 + (size_t)l * NW, w1a + NW, (int)(NW / 4));
        }
        if (skq && l > 0) {
            ln_wave<0, 1><<<dim3(MROWS / 4), dim3(256), 0, stream>>>(
                x, nullptr, x, hbf, ln1g + l * DIM, ln1b + l * DIM, parts, b2 + (l - 1) * DIM);
        } else {
            ln_wave<0, 0><<<dim3(MROWS / 4), dim3(256), 0, stream>>>(
                x, nullptr, nullptr, hbf, ln1g + l * DIM, ln1b + l * DIM, nullptr, nullptr);
        }
        qkv_mfma<<<dim3(50, 12), dim3(256), 0, stream>>>(
            hbf, wqkvb + (size_t)l * NHEAD * 12288,
            bq + l * NHEAD * DH, bk + l * NHEAD * DH, bv + l * NHEAD * DH,
            qb, kb, vb);
        attn_mfma<<<dim3(NBATCH, NHEAD), dim3(256), 0, stream>>>(qb, kb, vb, h);
        ln_wave<1, 0><<<dim3(MROWS / 4), dim3(256), 0, stream>>>(
            x, h, x, h2bf, ln2g + l * DIM, ln2b + l * DIM, nullptr, nullptr);
        gemm_bf<1><<<dim3(50, 24), dim3(256), 0, stream>>>(
            h2bf, wl1, b1 + l * MDIM, mid, nullptr, MROWS, MDIM, DIM);
        if (skq) {
            gemm_splitk<<<dim3(50, 6, SPLITK), dim3(256), 0, stream>>>(
                mid, wl2, parts, MROWS, DIM, MDIM);
        } else {
            gemm_bf<2><<<dim3(50, 6), dim3(256), 0, stream>>>(
                mid, wl2, b2 + l * DIM, x, x, MROWS, DIM, MDIM);
        }
    }
    if (skq) {
        reduceK<<<dim3(MROWS / 4), dim3(256), 0, stream>>>(x, parts, b2 + (NLAYER - 1) * DIM);
    }

    head_kernel<<<dim3(NBATCH, 250), dim3(256), 0, stream>>>(x, Wh, bh, logits);
    softmax_kernel<<<dim3(NBATCH), dim3(256), 0, stream>>>(logits, out);
}